// Round 15
// baseline (607.120 us; speedup 1.0000x reference)
//
#include <hip/hip_runtime.h>
#include <hip/hip_bf16.h>
#include <cstdint>

typedef __attribute__((ext_vector_type(8))) short short8;
typedef __attribute__((ext_vector_type(4))) float f32x4;

#define NS 512
#define NB 32
#define NE 768
#define NH 128
#define NT 15
#define NM (NB*NS)      // 16384 rows, m = b*512 + s

#define LOG2E  1.4426950408889634f
#define LOG2E2 2.8853900817779268f

__device__ __forceinline__ float bflo(unsigned int u){ return __builtin_bit_cast(float, u << 16); }
__device__ __forceinline__ float bfhi(unsigned int u){ return __builtin_bit_cast(float, u & 0xffff0000u); }
__device__ __forceinline__ float bfu(unsigned short u){ return __builtin_bit_cast(float, (unsigned)u << 16); }

__device__ __forceinline__ float rcpf_(float x){
#if __has_builtin(__builtin_amdgcn_rcpf)
  return __builtin_amdgcn_rcpf(x);
#else
  return __fdividef(1.f, x);
#endif
}
__device__ __forceinline__ float ex2_(float x){
#if __has_builtin(__builtin_amdgcn_exp2f)
  return __builtin_amdgcn_exp2f(x);
#else
  return exp2f(x);
#endif
}

// raw workgroup barrier: LDS-drain only, global loads/stores stay in flight.
__device__ __forceinline__ void lds_barrier() {
  asm volatile("s_waitcnt lgkmcnt(0)" ::: "memory");
  __builtin_amdgcn_s_barrier();
  asm volatile("" ::: "memory");
}

__device__ __forceinline__ void gload16(const void* g, void* l) {
#if __has_builtin(__builtin_amdgcn_global_load_lds)
  __builtin_amdgcn_global_load_lds((const __attribute__((address_space(1))) void*)g,
                                   (__attribute__((address_space(3))) void*)l, 16, 0, 0);
#else
  *(uint4*)l = *(const uint4*)g;
#endif
}

// ---------------- converts ----------------
__global__ void cvt_bf16_kernel(const float* __restrict__ in,
                                __hip_bfloat16* __restrict__ out, int n4) {
  int i = blockIdx.x*blockDim.x + threadIdx.x;
  int stride = gridDim.x*blockDim.x;
  for (int j = i; j < n4; j += stride) {
    float4 v = ((const float4*)in)[j];
    ushort4 o;
    o.x = __builtin_bit_cast(unsigned short, __float2bfloat16(v.x));
    o.y = __builtin_bit_cast(unsigned short, __float2bfloat16(v.y));
    o.z = __builtin_bit_cast(unsigned short, __float2bfloat16(v.z));
    o.w = __builtin_bit_cast(unsigned short, __float2bfloat16(v.w));
    ((ushort4*)out)[j] = o;
  }
}

// Fused weight prep: one block per permuted row n = dir*512 + (j*4+g).
// Writes Wih row (768, scaled), Whh row (128, scaled), bias entry (scaled).
// Scale: log2e for gates i,f,o; 2*log2e for g -> activations use exp2 directly.
__global__ void prep_weights_kernel(
    const float* __restrict__ wihf, const float* __restrict__ wihb,
    const float* __restrict__ whhf, const float* __restrict__ whhb,
    const float* __restrict__ bihf, const float* __restrict__ bhhf,
    const float* __restrict__ bihb, const float* __restrict__ bhhb,
    __hip_bfloat16* __restrict__ wihp,   // [1024][768]
    __hip_bfloat16* __restrict__ whhp,   // [1024][128]
    float* __restrict__ biasp)           // [1024]
{
  const int n = blockIdx.x;           // 0..1023
  const int dir = n >> 9, cc = n & 511, j = cc >> 2, g = cc & 3;
  const float fac = (g == 2) ? LOG2E2 : LOG2E;
  const int srow = g*128 + j;
  const float* si = (dir ? wihb : wihf) + (size_t)srow*768;
  __hip_bfloat16* di = wihp + (size_t)n*768;
  for (int e = threadIdx.x; e < 768; e += 256) di[e] = __float2bfloat16(si[e]*fac);
  const float* sh = (dir ? whhb : whhf) + (size_t)srow*128;
  __hip_bfloat16* dh = whhp + (size_t)n*128;
  if (threadIdx.x < 128) dh[threadIdx.x] = __float2bfloat16(sh[threadIdx.x]*fac);
  if (threadIdx.x == 0)
    biasp[n] = fac * (dir ? (bihb[srow] + bhhb[srow]) : (bihf[srow] + bhhf[srow]));
}

// ---------------- xproj GEMM: A[16384x768] @ Bw[1024x768]^T -> xqd[2][NM][512] ----------------
__global__ __launch_bounds__(256, 2) void gemm_xproj(
    const __hip_bfloat16* __restrict__ A,
    const __hip_bfloat16* __restrict__ Bw,
    const float* __restrict__ biasp,
    __hip_bfloat16* __restrict__ xqd)        // [2][NM][512] packed j*4+g, scaled
{
  __shared__ __align__(16) __hip_bfloat16 As[128*64];
  __shared__ __align__(16) __hip_bfloat16 Bs[128*64];
  const int bm = blockIdx.x * 128;
  const int bn = blockIdx.y * 128;
  const int tid = threadIdx.x;
  const int lane = tid & 63;
  const int wv = tid >> 6;
  const int wr = wv >> 1, wc = wv & 1;
  char* AsB = (char*)As;
  char* BsB = (char*)Bs;
  const char* Ab = (const char*)A;
  const char* Bb = (const char*)Bw;
  f32x4 acc[4][4] = {};

  for (int kt = 0; kt < 12; ++kt) {
    const int k0 = kt * 64;
    __syncthreads();
    #pragma unroll
    for (int i = 0; i < 4; ++i) {
      int fb = i*4096 + tid*16;
      int r  = fb >> 7;
      int cb = fb & 127;
      gload16(Ab + ((size_t)(bm + r)*768 + k0)*2 + cb, AsB + fb);
      gload16(Bb + ((size_t)(bn + r)*768 + k0)*2 + cb, BsB + fb);
    }
    __syncthreads();
    #pragma unroll
    for (int ks = 0; ks < 2; ++ks) {
      const int krow = ks*32 + ((lane >> 4) << 3);
      short8 af[4], bfr[4];
      #pragma unroll
      for (int m = 0; m < 4; ++m) {
        int row = wr*64 + m*16 + (lane & 15);
        af[m] = *(const short8*)(AsB + (row*64 + krow)*2);
      }
      #pragma unroll
      for (int n = 0; n < 4; ++n) {
        int row = wc*64 + n*16 + (lane & 15);
        bfr[n] = *(const short8*)(BsB + (row*64 + krow)*2);
      }
      #pragma unroll
      for (int m = 0; m < 4; ++m)
        #pragma unroll
        for (int n = 0; n < 4; ++n)
          acc[m][n] = __builtin_amdgcn_mfma_f32_16x16x32_bf16(af[m], bfr[n], acc[m][n], 0, 0, 0);
    }
  }
  #pragma unroll
  for (int m = 0; m < 4; ++m) {
    #pragma unroll
    for (int n = 0; n < 4; ++n) {
      const int col = bn + wc*64 + n*16 + (lane & 15);
      const float bv = biasp[col];
      const int dir = col >> 9;
      const int cc  = col & 511;
      #pragma unroll
      for (int jj = 0; jj < 4; ++jj) {
        const int row = bm + wr*64 + m*16 + ((lane >> 4)*4 + jj);
        xqd[((size_t)dir*NM + row)*512 + cc] = __float2bfloat16(acc[m][n][jj] + bv);
      }
    }
  }
}

// ---------------- LSTM: R13 two-phase structure, refill-after-consume x ring ----------------
// 16 blocks = (dir, bg), 4 batches each, 512 threads = 8 waves.
// Phase A: z[512x16] = Whhp @ h via MFMA (weights AGPR-pinned); z -> swizzled z_lds.
// Phase B: thread (b4=t&3, j=t>>2) computes one h; h -> next B-frag buffer + global (bf16).
// x ring: slot consumed FIRST, then refill load issued DIRECTLY into the same
// register (no rotation copy -> no same-step vmcnt wait; store acks never drained).
__global__ __launch_bounds__(512) __attribute__((amdgpu_waves_per_eu(1, 2)))
void lstm_mfma(
    const __hip_bfloat16* __restrict__ xqd,   // [2][NM][512] packed j*4+g, bias folded, scaled
    const __hip_bfloat16* __restrict__ whhp,  // [2][512][128] permuted rows, scaled
    unsigned short* __restrict__ hf,          // [NM][128] bf16
    unsigned short* __restrict__ hb)          // [NM][128] bf16
{
  __shared__ __align__(16) char hfrag[2*4224];   // [buf][kc:1056B][lane:16B] B-frag layout
  __shared__ __align__(16) float z_lds[4*520];   // [b][4*swz(j)] f32x4, swizzled

  const int bid = blockIdx.x;
  const int dir = bid >> 3, bg = bid & 7;
  const int t = threadIdx.x;
  const int w = t >> 6, l = t & 63;
  const int ln = l & 15, lp = l >> 4;

  // A-fragments (weights): wave w rows (w*4+r)*16+ln, k = kc*32 + lp*8 + e.
  uint4 afu[4][4];
  {
    const char* wbase = (const char*)(whhp + (size_t)dir*512*128);
    #pragma unroll
    for (int r = 0; r < 4; ++r) {
      const int row = (w*4 + r)*16 + ln;
      #pragma unroll
      for (int kc = 0; kc < 4; ++kc)
        afu[r][kc] = *(const uint4*)(wbase + ((size_t)row*128 + lp*8 + kc*32)*2);
    }
  }

  for (int i = t; i < 2*4224/4; i += 512) ((int*)hfrag)[i] = 0;

  // phase-B identity
  const int b4 = t & 3, j = t >> 2;
  const int bsafe = bg*4 + b4;
  const int jsw = j ^ ((j >> 3) & 7);
  const int woff = (j >> 5)*1056 + ((j >> 3) & 3)*256 + b4*16 + (j & 7)*2;
  const int sdir = dir ? -1 : 1;
  const int s0 = dir ? 511 : 0;
  const ptrdiff_t xstep = (ptrdiff_t)sdir*512;
  const ptrdiff_t hstep = (ptrdiff_t)sdir*128;
  const __hip_bfloat16* xbase = xqd + ((size_t)dir*NM + (size_t)bsafe*512)*512
                                + (ptrdiff_t)s0*512 + j*4;
  unsigned short* hout = (dir ? hb : hf) + (size_t)bsafe*512*128 + (ptrdiff_t)s0*128 + j;

  float c = 0.f;

  // depth-4 x ring
  uint2 x0 = *(const uint2*)(xbase);
  uint2 x1 = *(const uint2*)(xbase + xstep);
  uint2 x2 = *(const uint2*)(xbase + 2*xstep);
  uint2 x3 = *(const uint2*)(xbase + 3*xstep);
  const __hip_bfloat16* xpre = xbase + 4*xstep;   // next address to fetch
  __syncthreads();   // prologue only

  int buf = 0;

  auto STEP = [&](uint2& xc, bool pf) {
    // ---- phase A: B-fragments (lane-linear, conflict-free) + 16 MFMA ----
    short8 bfv[4];
    #pragma unroll
    for (int kc = 0; kc < 4; ++kc)
      bfv[kc] = *(const short8*)(hfrag + buf*4224 + kc*1056 + l*16);

    f32x4 acc[4];
    #pragma unroll
    for (int r = 0; r < 4; ++r) {
      acc[r] = f32x4{0.f, 0.f, 0.f, 0.f};
      #pragma unroll
      for (int kc = 0; kc < 4; ++kc)
        acc[r] = __builtin_amdgcn_mfma_f32_16x16x32_bf16(
                   __builtin_bit_cast(short8, afu[r][kc]), bfv[kc], acc[r], 0, 0, 0);
    }

    // publish z (real batch cols ln<4 only), XOR-swizzled -> conflict-free
    if (ln < 4) {
      #pragma unroll
      for (int r = 0; r < 4; ++r) {
        const int jw = (w*4 + r)*4 + lp;
        const int js = jw ^ ((jw >> 3) & 7);
        *(f32x4*)&z_lds[ln*520 + 4*js] = acc[r];
      }
    }
    lds_barrier();

    // ---- phase B: one h per thread (exp2 forms, inputs pre-scaled) ----
    const f32x4 zv = *(const f32x4*)&z_lds[b4*520 + 4*jsw];
    const float zi = zv[0] + bflo(xc.x);
    const float zf = zv[1] + bfhi(xc.x);
    const float zg = zv[2] + bflo(xc.y);
    const float zo = zv[3] + bfhi(xc.y);
    const float I = rcpf_(1.f + ex2_(-zi));
    const float F = rcpf_(1.f + ex2_(-zf));
    const float G = 1.f - 2.f*rcpf_(ex2_(zg) + 1.f);
    const float O = rcpf_(1.f + ex2_(-zo));
    c = F*c + I*G;
    const float h = O*(1.f - 2.f*rcpf_(ex2_(c*LOG2E2) + 1.f));

    const unsigned short hbits =
        __builtin_bit_cast(unsigned short, __float2bfloat16(h));
    *(short*)(hfrag + (buf ^ 1)*4224 + woff) = (short)hbits;
    *hout = hbits;                     // fire-and-forget bf16 store
    hout += hstep;

    // refill AFTER consume: load directly into xc's register (no copy, no
    // same-step wait; consumed 4 steps later at vmcnt(~6))
    if (pf) { xc = *(const uint2*)xpre; xpre += xstep; }
    lds_barrier();
    buf ^= 1;
  };

  for (int it = 0; it < 127; ++it) {   // 508 steps with prefetch
    // AGPR pin (R9-proven residency mechanism)
    #pragma unroll
    for (int r = 0; r < 4; ++r)
      #pragma unroll
      for (int kc = 0; kc < 4; ++kc)
        asm volatile("" : "+a"(afu[r][kc].x), "+a"(afu[r][kc].y),
                          "+a"(afu[r][kc].z), "+a"(afu[r][kc].w));
    STEP(x0, true);
    STEP(x1, true);
    STEP(x2, true);
    STEP(x3, true);
  }
  // epilogue: last 4 steps, no prefetch
  STEP(x0, false);
  STEP(x1, false);
  STEP(x2, false);
  STEP(x3, false);
}

// ---------------- emissions: em[m][t] = [hf|hb][m] . Wp[t] + bp[t]  (bf16 h) ----------------
__global__ __launch_bounds__(256) void em_kernel(
    const unsigned short* __restrict__ hf, const unsigned short* __restrict__ hb,
    const float* __restrict__ Wp, const float* __restrict__ bp,
    float* __restrict__ em)
{
  __shared__ float wps[15*256];
  __shared__ float bps[15];
  const int tid = threadIdx.x;
  for (int i = tid; i < 15*256; i += 256) wps[i] = Wp[i];
  if (tid < 15) bps[tid] = bp[tid];
  __syncthreads();
  const size_t m = (size_t)blockIdx.x*256 + tid;
  float acc[15];
  #pragma unroll
  for (int t2 = 0; t2 < 15; ++t2) acc[t2] = bps[t2];
  const ushort4* hf4 = (const ushort4*)(hf + m*128);
  const ushort4* hb4 = (const ushort4*)(hb + m*128);
  for (int kc = 0; kc < 32; ++kc) {
    const ushort4 hv = hf4[kc];
    const float h0 = bfu(hv.x), h1 = bfu(hv.y), h2 = bfu(hv.z), h3 = bfu(hv.w);
    #pragma unroll
    for (int t2 = 0; t2 < 15; ++t2)
      acc[t2] += h0*wps[t2*256 + kc*4+0] + h1*wps[t2*256 + kc*4+1]
               + h2*wps[t2*256 + kc*4+2] + h3*wps[t2*256 + kc*4+3];
  }
  for (int kc = 0; kc < 32; ++kc) {
    const ushort4 hv = hb4[kc];
    const float h0 = bfu(hv.x), h1 = bfu(hv.y), h2 = bfu(hv.z), h3 = bfu(hv.w);
    #pragma unroll
    for (int t2 = 0; t2 < 15; ++t2)
      acc[t2] += h0*wps[t2*256 + 128 + kc*4+0] + h1*wps[t2*256 + 128 + kc*4+1]
               + h2*wps[t2*256 + 128 + kc*4+2] + h3*wps[t2*256 + 128 + kc*4+3];
  }
  float* eo = em + m*15;
  #pragma unroll
  for (int t2 = 0; t2 < 15; ++t2) eo[t2] = acc[t2];
}

// ---------------- CRF NLL: one block (1 wave) per batch -> partial per b ----------------
__global__ __launch_bounds__(64) void crf_kernel(
    const float* __restrict__ em,
    const int* __restrict__ tags, const int* __restrict__ mask,
    const float* __restrict__ trans, const float* __restrict__ start_t,
    const float* __restrict__ end_t, float* __restrict__ nllb)
{
  __shared__ __align__(16) float ems[512*15];
  __shared__ float trs[225];
  __shared__ int tgs[512];
  __shared__ int mks[512];
  const int b = blockIdx.x, j = threadIdx.x;
  const float* emb = em + (size_t)b*512*15;
  {
    const float4* s4 = (const float4*)emb;
    float4* d4 = (float4*)ems;
    for (int i = j; i < 512*15/4; i += 64) d4[i] = s4[i];
    for (int i = j; i < 512; i += 64) { tgs[i] = tags[b*512+i]; mks[i] = mask[b*512+i]; }
    for (int i = j; i < 225; i += 64) trs[i] = trans[i];
  }
  __syncthreads();

  float trc[15];
  #pragma unroll
  for (int i = 0; i < 15; ++i) trc[i] = (j < 15) ? trs[i*15 + j] : 0.f;

  float alpha = (j < 15) ? (start_t[j] + ems[j]) : -3.0e38f;
  for (int s = 1; s < 512; ++s) {
    const float emv = (j < 15) ? ems[s*15 + j] : 0.f;
    const int msk = mks[s];
    float v[15];
    // alpha_i broadcast via v_readlane (SGPR) instead of 15 ds_bpermute shuffles
    #pragma unroll
    for (int i = 0; i < 15; ++i) {
#if __has_builtin(__builtin_amdgcn_readlane)
      const float ai = __builtin_bit_cast(float,
          __builtin_amdgcn_readlane(__builtin_bit_cast(int, alpha), i));
#else
      const float ai = __shfl(alpha, i, 64);
#endif
      v[i] = ai + trc[i];
    }
    const float t01 = fmaxf(v[0], v[1]),  t23 = fmaxf(v[2], v[3]);
    const float t45 = fmaxf(v[4], v[5]),  t67 = fmaxf(v[6], v[7]);
    const float t89 = fmaxf(v[8], v[9]),  tab = fmaxf(v[10], v[11]);
    const float tcd = fmaxf(v[12], v[13]);
    const float q0 = fmaxf(t01, t23), q1 = fmaxf(t45, t67);
    const float q2 = fmaxf(t89, tab), q3 = fmaxf(tcd, v[14]);
    const float mx = fmaxf(fmaxf(q0, q1), fmaxf(q2, q3));
    float e[15];
    #pragma unroll
    for (int i = 0; i < 15; ++i) e[i] = __expf(v[i] - mx);
    const float s01 = e[0]+e[1], s23 = e[2]+e[3], s45 = e[4]+e[5], s67 = e[6]+e[7];
    const float s89 = e[8]+e[9], sab = e[10]+e[11], scd = e[12]+e[13];
    const float u0 = s01+s23, u1 = s45+s67, u2 = s89+sab, u3 = scd+e[14];
    const float sum = (u0+u1) + (u2+u3);
    const float nxt = emv + mx + __logf(sum);
    if (msk > 0 && j < 15) alpha = nxt;
  }
  float vz = (j < 15) ? (alpha + end_t[j]) : -3.0e38f;
  float mz = vz;
  #pragma unroll
  for (int off = 32; off > 0; off >>= 1) mz = fmaxf(mz, __shfl_xor(mz, off, 64));
  float se = (j < 15) ? __expf(vz - mz) : 0.f;
  #pragma unroll
  for (int off = 32; off > 0; off >>= 1) se += __shfl_xor(se, off, 64);
  const float logZ = mz + __logf(se);

  float sc = 0.f; int cnt = 0;
  for (int s = j; s < 512; s += 64) cnt += (mks[s] ? 1 : 0);
  for (int s = 1 + j; s < 512; s += 64) {
    if (mks[s]) {
      const int tp = tgs[s-1], tc = tgs[s];
      sc += trs[tp*15 + tc] + ems[s*15 + tc];
    }
  }
  #pragma unroll
  for (int off = 32; off > 0; off >>= 1) {
    sc  += __shfl_xor(sc, off, 64);
    cnt += __shfl_xor(cnt, off, 64);
  }
  if (j == 0) {
    const int t0 = tgs[0];
    sc += start_t[t0] + ems[t0];
    int last = cnt - 1; if (last < 0) last = 0;
    sc += end_t[tgs[last]];
    nllb[b] = logZ - sc;
  }
}

__global__ __launch_bounds__(64) void nll_reduce_kernel(const float* __restrict__ nllb,
                                                        float* __restrict__ out) {
  const int j = threadIdx.x;
  float v = (j < 32) ? nllb[j] : 0.f;
  #pragma unroll
  for (int off = 32; off > 0; off >>= 1) v += __shfl_xor(v, off, 64);
  if (j == 0) out[0] = v;
}

// ---------------- launch ----------------
extern "C" void kernel_launch(void* const* d_in, const int* in_sizes, int n_in,
                              void* d_out, int out_size, void* d_ws, size_t ws_size,
                              hipStream_t stream) {
  const float* x      = (const float*)d_in[0];
  const int*   tags   = (const int*)d_in[1];
  const int*   mask   = (const int*)d_in[2];
  const float* Wih_f  = (const float*)d_in[3];
  const float* Whh_f  = (const float*)d_in[4];
  const float* bih_f  = (const float*)d_in[5];
  const float* bhh_f  = (const float*)d_in[6];
  const float* Wih_b  = (const float*)d_in[7];
  const float* Whh_b  = (const float*)d_in[8];
  const float* bih_b  = (const float*)d_in[9];
  const float* bhh_b  = (const float*)d_in[10];
  const float* Wp     = (const float*)d_in[11];
  const float* bp     = (const float*)d_in[12];
  const float* trans  = (const float*)d_in[13];
  const float* start_t= (const float*)d_in[14];
  const float* end_t  = (const float*)d_in[15];
  float* out = (float*)d_out;

  char* ws = (char*)d_ws;
  size_t off = 0;
  auto alloc = [&](size_t bytes) { char* p = ws + off; off += (bytes + 255) & ~(size_t)255; return p; };
  __hip_bfloat16* xbf   = (__hip_bfloat16*)alloc((size_t)NM*NE*2);        // 25.2 MB
  __hip_bfloat16* Wihbf = (__hip_bfloat16*)alloc((size_t)1024*NE*2);      // 1.6 MB
  __hip_bfloat16* whhp  = (__hip_bfloat16*)alloc((size_t)2*512*128*2);    // 0.26 MB
  float*          biasp = (float*)alloc(1024*4);
  __hip_bfloat16* xqd   = (__hip_bfloat16*)alloc((size_t)2*NM*512*2);     // 33.6 MB
  unsigned short* hf    = (unsigned short*)alloc((size_t)NM*128*2);       // 4.2 MB
  unsigned short* hb    = (unsigned short*)alloc((size_t)NM*128*2);       // 4.2 MB
  float*          em    = (float*)alloc((size_t)NM*15*4);                 // 1.0 MB
  float*          nllb  = (float*)alloc(32*4);
  (void)ws_size; (void)in_sizes; (void)n_in; (void)out_size;

  cvt_bf16_kernel<<<2048, 256, 0, stream>>>(x, xbf, NM*NE/4);
  prep_weights_kernel<<<1024, 256, 0, stream>>>(Wih_f, Wih_b, Whh_f, Whh_b,
                                                bih_f, bhh_f, bih_b, bhh_b,
                                                Wihbf, whhp, biasp);

  gemm_xproj<<<dim3(128, 8), 256, 0, stream>>>(xbf, Wihbf, biasp, xqd);
  lstm_mfma<<<16, 512, 0, stream>>>(xqd, whhp, hf, hb);
  em_kernel<<<64, 256, 0, stream>>>(hf, hb, Wp, bp, em);
  crf_kernel<<<32, 64, 0, stream>>>(em, tags, mask, trans, start_t, end_t, nllb);
  nll_reduce_kernel<<<1, 64, 0, stream>>>(nllb, out);
}

// Round 16
// 590.169 us; speedup vs baseline: 1.0287x; 1.0287x over previous
//
#include <hip/hip_runtime.h>
#include <hip/hip_bf16.h>
#include <cstdint>

typedef __attribute__((ext_vector_type(8))) short short8;
typedef __attribute__((ext_vector_type(4))) float f32x4;

#define NS 512
#define NB 32
#define NE 768
#define NH 128
#define NT 15
#define NM (NB*NS)      // 16384 rows, m = b*512 + s

#define LOG2E  1.4426950408889634f
#define LOG2E2 2.8853900817779268f

__device__ __forceinline__ float bflo(unsigned int u){ return __builtin_bit_cast(float, u << 16); }
__device__ __forceinline__ float bfhi(unsigned int u){ return __builtin_bit_cast(float, u & 0xffff0000u); }
__device__ __forceinline__ float bfu(unsigned short u){ return __builtin_bit_cast(float, (unsigned)u << 16); }

__device__ __forceinline__ float rcpf_(float x){
#if __has_builtin(__builtin_amdgcn_rcpf)
  return __builtin_amdgcn_rcpf(x);
#else
  return __fdividef(1.f, x);
#endif
}
__device__ __forceinline__ float ex2_(float x){
#if __has_builtin(__builtin_amdgcn_exp2f)
  return __builtin_amdgcn_exp2f(x);
#else
  return exp2f(x);
#endif
}

// raw workgroup barrier: LDS-drain only, global loads/stores stay in flight.
__device__ __forceinline__ void lds_barrier() {
  asm volatile("s_waitcnt lgkmcnt(0)" ::: "memory");
  __builtin_amdgcn_s_barrier();
  asm volatile("" ::: "memory");
}

__device__ __forceinline__ void gload16(const void* g, void* l) {
#if __has_builtin(__builtin_amdgcn_global_load_lds)
  __builtin_amdgcn_global_load_lds((const __attribute__((address_space(1))) void*)g,
                                   (__attribute__((address_space(3))) void*)l, 16, 0, 0);
#else
  *(uint4*)l = *(const uint4*)g;
#endif
}

// ---------------- converts ----------------
__global__ void cvt_bf16_kernel(const float* __restrict__ in,
                                __hip_bfloat16* __restrict__ out, int n4) {
  int i = blockIdx.x*blockDim.x + threadIdx.x;
  int stride = gridDim.x*blockDim.x;
  for (int j = i; j < n4; j += stride) {
    float4 v = ((const float4*)in)[j];
    ushort4 o;
    o.x = __builtin_bit_cast(unsigned short, __float2bfloat16(v.x));
    o.y = __builtin_bit_cast(unsigned short, __float2bfloat16(v.y));
    o.z = __builtin_bit_cast(unsigned short, __float2bfloat16(v.z));
    o.w = __builtin_bit_cast(unsigned short, __float2bfloat16(v.w));
    ((ushort4*)out)[j] = o;
  }
}

// Fused weight prep: one block per permuted row n = dir*512 + (j*4+g).
// Scale: log2e for gates i,f,o; 2*log2e for g -> activations use exp2 directly.
__global__ void prep_weights_kernel(
    const float* __restrict__ wihf, const float* __restrict__ wihb,
    const float* __restrict__ whhf, const float* __restrict__ whhb,
    const float* __restrict__ bihf, const float* __restrict__ bhhf,
    const float* __restrict__ bihb, const float* __restrict__ bhhb,
    __hip_bfloat16* __restrict__ wihp,   // [1024][768]
    __hip_bfloat16* __restrict__ whhp,   // [1024][128]
    float* __restrict__ biasp)           // [1024]
{
  const int n = blockIdx.x;           // 0..1023
  const int dir = n >> 9, cc = n & 511, j = cc >> 2, g = cc & 3;
  const float fac = (g == 2) ? LOG2E2 : LOG2E;
  const int srow = g*128 + j;
  const float* si = (dir ? wihb : wihf) + (size_t)srow*768;
  __hip_bfloat16* di = wihp + (size_t)n*768;
  for (int e = threadIdx.x; e < 768; e += 256) di[e] = __float2bfloat16(si[e]*fac);
  const float* sh = (dir ? whhb : whhf) + (size_t)srow*128;
  __hip_bfloat16* dh = whhp + (size_t)n*128;
  if (threadIdx.x < 128) dh[threadIdx.x] = __float2bfloat16(sh[threadIdx.x]*fac);
  if (threadIdx.x == 0)
    biasp[n] = fac * (dir ? (bihb[srow] + bhhb[srow]) : (bihf[srow] + bhhf[srow]));
}

// ---------------- xproj GEMM: A[16384x768] @ Bw[1024x768]^T -> xqd[2][NM][512] ----------------
// occupancy 4 blocks/CU: grid is 1024 blocks = 4/CU -> full co-residency,
// inter-block overlap hides the per-K-step barrier drains.
__global__ __launch_bounds__(256, 4) void gemm_xproj(
    const __hip_bfloat16* __restrict__ A,
    const __hip_bfloat16* __restrict__ Bw,
    const float* __restrict__ biasp,
    __hip_bfloat16* __restrict__ xqd)        // [2][NM][512] packed j*4+g, scaled
{
  __shared__ __align__(16) __hip_bfloat16 As[128*64];
  __shared__ __align__(16) __hip_bfloat16 Bs[128*64];
  const int bm = blockIdx.x * 128;
  const int bn = blockIdx.y * 128;
  const int tid = threadIdx.x;
  const int lane = tid & 63;
  const int wv = tid >> 6;
  const int wr = wv >> 1, wc = wv & 1;
  char* AsB = (char*)As;
  char* BsB = (char*)Bs;
  const char* Ab = (const char*)A;
  const char* Bb = (const char*)Bw;
  f32x4 acc[4][4] = {};

  for (int kt = 0; kt < 12; ++kt) {
    const int k0 = kt * 64;
    __syncthreads();
    #pragma unroll
    for (int i = 0; i < 4; ++i) {
      int fb = i*4096 + tid*16;
      int r  = fb >> 7;
      int cb = fb & 127;
      gload16(Ab + ((size_t)(bm + r)*768 + k0)*2 + cb, AsB + fb);
      gload16(Bb + ((size_t)(bn + r)*768 + k0)*2 + cb, BsB + fb);
    }
    __syncthreads();
    #pragma unroll
    for (int ks = 0; ks < 2; ++ks) {
      const int krow = ks*32 + ((lane >> 4) << 3);
      short8 af[4], bfr[4];
      #pragma unroll
      for (int m = 0; m < 4; ++m) {
        int row = wr*64 + m*16 + (lane & 15);
        af[m] = *(const short8*)(AsB + (row*64 + krow)*2);
      }
      #pragma unroll
      for (int n = 0; n < 4; ++n) {
        int row = wc*64 + n*16 + (lane & 15);
        bfr[n] = *(const short8*)(BsB + (row*64 + krow)*2);
      }
      #pragma unroll
      for (int m = 0; m < 4; ++m)
        #pragma unroll
        for (int n = 0; n < 4; ++n)
          acc[m][n] = __builtin_amdgcn_mfma_f32_16x16x32_bf16(af[m], bfr[n], acc[m][n], 0, 0, 0);
    }
  }
  #pragma unroll
  for (int m = 0; m < 4; ++m) {
    #pragma unroll
    for (int n = 0; n < 4; ++n) {
      const int col = bn + wc*64 + n*16 + (lane & 15);
      const float bv = biasp[col];
      const int dir = col >> 9;
      const int cc  = col & 511;
      #pragma unroll
      for (int jj = 0; jj < 4; ++jj) {
        const int row = bm + wr*64 + m*16 + ((lane >> 4)*4 + jj);
        xqd[((size_t)dir*NM + row)*512 + cc] = __float2bfloat16(acc[m][n][jj] + bv);
      }
    }
  }
}

// ---------------- LSTM: frozen R15 structure (two-phase, refill-after-consume) ----------------
__global__ __launch_bounds__(512) __attribute__((amdgpu_waves_per_eu(1, 2)))
void lstm_mfma(
    const __hip_bfloat16* __restrict__ xqd,   // [2][NM][512] packed j*4+g, bias folded, scaled
    const __hip_bfloat16* __restrict__ whhp,  // [2][512][128] permuted rows, scaled
    unsigned short* __restrict__ hf,          // [NM][128] bf16
    unsigned short* __restrict__ hb)          // [NM][128] bf16
{
  __shared__ __align__(16) char hfrag[2*4224];   // [buf][kc:1056B][lane:16B] B-frag layout
  __shared__ __align__(16) float z_lds[4*520];   // [b][4*swz(j)] f32x4, swizzled

  const int bid = blockIdx.x;
  const int dir = bid >> 3, bg = bid & 7;
  const int t = threadIdx.x;
  const int w = t >> 6, l = t & 63;
  const int ln = l & 15, lp = l >> 4;

  // A-fragments (weights): wave w rows (w*4+r)*16+ln, k = kc*32 + lp*8 + e.
  uint4 afu[4][4];
  {
    const char* wbase = (const char*)(whhp + (size_t)dir*512*128);
    #pragma unroll
    for (int r = 0; r < 4; ++r) {
      const int row = (w*4 + r)*16 + ln;
      #pragma unroll
      for (int kc = 0; kc < 4; ++kc)
        afu[r][kc] = *(const uint4*)(wbase + ((size_t)row*128 + lp*8 + kc*32)*2);
    }
  }

  for (int i = t; i < 2*4224/4; i += 512) ((int*)hfrag)[i] = 0;

  // phase-B identity
  const int b4 = t & 3, j = t >> 2;
  const int bsafe = bg*4 + b4;
  const int jsw = j ^ ((j >> 3) & 7);
  const int woff = (j >> 5)*1056 + ((j >> 3) & 3)*256 + b4*16 + (j & 7)*2;
  const int sdir = dir ? -1 : 1;
  const int s0 = dir ? 511 : 0;
  const ptrdiff_t xstep = (ptrdiff_t)sdir*512;
  const ptrdiff_t hstep = (ptrdiff_t)sdir*128;
  const __hip_bfloat16* xbase = xqd + ((size_t)dir*NM + (size_t)bsafe*512)*512
                                + (ptrdiff_t)s0*512 + j*4;
  unsigned short* hout = (dir ? hb : hf) + (size_t)bsafe*512*128 + (ptrdiff_t)s0*128 + j;

  float c = 0.f;

  // depth-4 x ring
  uint2 x0 = *(const uint2*)(xbase);
  uint2 x1 = *(const uint2*)(xbase + xstep);
  uint2 x2 = *(const uint2*)(xbase + 2*xstep);
  uint2 x3 = *(const uint2*)(xbase + 3*xstep);
  const __hip_bfloat16* xpre = xbase + 4*xstep;   // next address to fetch
  __syncthreads();   // prologue only

  int buf = 0;

  auto STEP = [&](uint2& xc, bool pf) {
    // ---- phase A: B-fragments (lane-linear, conflict-free) + 16 MFMA ----
    short8 bfv[4];
    #pragma unroll
    for (int kc = 0; kc < 4; ++kc)
      bfv[kc] = *(const short8*)(hfrag + buf*4224 + kc*1056 + l*16);

    f32x4 acc[4];
    #pragma unroll
    for (int r = 0; r < 4; ++r) {
      acc[r] = f32x4{0.f, 0.f, 0.f, 0.f};
      #pragma unroll
      for (int kc = 0; kc < 4; ++kc)
        acc[r] = __builtin_amdgcn_mfma_f32_16x16x32_bf16(
                   __builtin_bit_cast(short8, afu[r][kc]), bfv[kc], acc[r], 0, 0, 0);
    }

    // publish z (real batch cols ln<4 only), XOR-swizzled -> conflict-free
    if (ln < 4) {
      #pragma unroll
      for (int r = 0; r < 4; ++r) {
        const int jw = (w*4 + r)*4 + lp;
        const int js = jw ^ ((jw >> 3) & 7);
        *(f32x4*)&z_lds[ln*520 + 4*js] = acc[r];
      }
    }
    lds_barrier();

    // ---- phase B: one h per thread (exp2 forms, inputs pre-scaled) ----
    const f32x4 zv = *(const f32x4*)&z_lds[b4*520 + 4*jsw];
    const float zi = zv[0] + bflo(xc.x);
    const float zf = zv[1] + bfhi(xc.x);
    const float zg = zv[2] + bflo(xc.y);
    const float zo = zv[3] + bfhi(xc.y);
    const float I = rcpf_(1.f + ex2_(-zi));
    const float F = rcpf_(1.f + ex2_(-zf));
    const float G = 1.f - 2.f*rcpf_(ex2_(zg) + 1.f);
    const float O = rcpf_(1.f + ex2_(-zo));
    c = F*c + I*G;
    const float h = O*(1.f - 2.f*rcpf_(ex2_(c*LOG2E2) + 1.f));

    const unsigned short hbits =
        __builtin_bit_cast(unsigned short, __float2bfloat16(h));
    *(short*)(hfrag + (buf ^ 1)*4224 + woff) = (short)hbits;
    *hout = hbits;                     // fire-and-forget bf16 store
    hout += hstep;

    // refill AFTER consume: load directly into xc's register
    if (pf) { xc = *(const uint2*)xpre; xpre += xstep; }
    lds_barrier();
    buf ^= 1;
  };

  for (int it = 0; it < 127; ++it) {   // 508 steps with prefetch
    // AGPR pin (R9-proven residency mechanism)
    #pragma unroll
    for (int r = 0; r < 4; ++r)
      #pragma unroll
      for (int kc = 0; kc < 4; ++kc)
        asm volatile("" : "+a"(afu[r][kc].x), "+a"(afu[r][kc].y),
                          "+a"(afu[r][kc].z), "+a"(afu[r][kc].w));
    STEP(x0, true);
    STEP(x1, true);
    STEP(x2, true);
    STEP(x3, true);
  }
  // epilogue: last 4 steps, no prefetch
  STEP(x0, false);
  STEP(x1, false);
  STEP(x2, false);
  STEP(x3, false);
}

// ---------------- emissions: em[m][t] = [hf|hb][m] . Wp[t] + bp[t]  (bf16 h) ----------------
__global__ __launch_bounds__(128) void em_kernel(
    const unsigned short* __restrict__ hf, const unsigned short* __restrict__ hb,
    const float* __restrict__ Wp, const float* __restrict__ bp,
    float* __restrict__ em)
{
  __shared__ float wps[15*256];
  __shared__ float bps[15];
  const int tid = threadIdx.x;
  for (int i = tid; i < 15*256; i += 128) wps[i] = Wp[i];
  if (tid < 15) bps[tid] = bp[tid];
  __syncthreads();
  const size_t m = (size_t)blockIdx.x*128 + tid;
  float acc[15];
  #pragma unroll
  for (int t2 = 0; t2 < 15; ++t2) acc[t2] = bps[t2];
  const ushort4* hf4 = (const ushort4*)(hf + m*128);
  const ushort4* hb4 = (const ushort4*)(hb + m*128);
  for (int kc = 0; kc < 32; ++kc) {
    const ushort4 hv = hf4[kc];
    const float h0 = bfu(hv.x), h1 = bfu(hv.y), h2 = bfu(hv.z), h3 = bfu(hv.w);
    #pragma unroll
    for (int t2 = 0; t2 < 15; ++t2)
      acc[t2] += h0*wps[t2*256 + kc*4+0] + h1*wps[t2*256 + kc*4+1]
               + h2*wps[t2*256 + kc*4+2] + h3*wps[t2*256 + kc*4+3];
  }
  for (int kc = 0; kc < 32; ++kc) {
    const ushort4 hv = hb4[kc];
    const float h0 = bfu(hv.x), h1 = bfu(hv.y), h2 = bfu(hv.z), h3 = bfu(hv.w);
    #pragma unroll
    for (int t2 = 0; t2 < 15; ++t2)
      acc[t2] += h0*wps[t2*256 + 128 + kc*4+0] + h1*wps[t2*256 + 128 + kc*4+1]
               + h2*wps[t2*256 + 128 + kc*4+2] + h3*wps[t2*256 + 128 + kc*4+3];
  }
  float* eo = em + m*15;
  #pragma unroll
  for (int t2 = 0; t2 < 15; ++t2) eo[t2] = acc[t2];
}

// ---------------- CRF NLL: one block (1 wave) per batch -> partial per b ----------------
__global__ __launch_bounds__(64) void crf_kernel(
    const float* __restrict__ em,
    const int* __restrict__ tags, const int* __restrict__ mask,
    const float* __restrict__ trans, const float* __restrict__ start_t,
    const float* __restrict__ end_t, float* __restrict__ nllb)
{
  __shared__ __align__(16) float ems[512*15];
  __shared__ float trs[225];
  __shared__ int tgs[512];
  __shared__ int mks[512];
  const int b = blockIdx.x, j = threadIdx.x;
  const float* emb = em + (size_t)b*512*15;
  {
    const float4* s4 = (const float4*)emb;
    float4* d4 = (float4*)ems;
    for (int i = j; i < 512*15/4; i += 64) d4[i] = s4[i];
    for (int i = j; i < 512; i += 64) { tgs[i] = tags[b*512+i]; mks[i] = mask[b*512+i]; }
    for (int i = j; i < 225; i += 64) trs[i] = trans[i];
  }
  __syncthreads();

  float trc[15];
  #pragma unroll
  for (int i = 0; i < 15; ++i) trc[i] = (j < 15) ? trs[i*15 + j] : 0.f;

  float alpha = (j < 15) ? (start_t[j] + ems[j]) : -3.0e38f;
  for (int s = 1; s < 512; ++s) {
    const float emv = (j < 15) ? ems[s*15 + j] : 0.f;
    const int msk = mks[s];
    float v[15];
    #pragma unroll
    for (int i = 0; i < 15; ++i) {
#if __has_builtin(__builtin_amdgcn_readlane)
      const float ai = __builtin_bit_cast(float,
          __builtin_amdgcn_readlane(__builtin_bit_cast(int, alpha), i));
#else
      const float ai = __shfl(alpha, i, 64);
#endif
      v[i] = ai + trc[i];
    }
    const float t01 = fmaxf(v[0], v[1]),  t23 = fmaxf(v[2], v[3]);
    const float t45 = fmaxf(v[4], v[5]),  t67 = fmaxf(v[6], v[7]);
    const float t89 = fmaxf(v[8], v[9]),  tab = fmaxf(v[10], v[11]);
    const float tcd = fmaxf(v[12], v[13]);
    const float q0 = fmaxf(t01, t23), q1 = fmaxf(t45, t67);
    const float q2 = fmaxf(t89, tab), q3 = fmaxf(tcd, v[14]);
    const float mx = fmaxf(fmaxf(q0, q1), fmaxf(q2, q3));
    float e[15];
    #pragma unroll
    for (int i = 0; i < 15; ++i) e[i] = __expf(v[i] - mx);
    const float s01 = e[0]+e[1], s23 = e[2]+e[3], s45 = e[4]+e[5], s67 = e[6]+e[7];
    const float s89 = e[8]+e[9], sab = e[10]+e[11], scd = e[12]+e[13];
    const float u0 = s01+s23, u1 = s45+s67, u2 = s89+sab, u3 = scd+e[14];
    const float sum = (u0+u1) + (u2+u3);
    const float nxt = emv + mx + __logf(sum);
    if (msk > 0 && j < 15) alpha = nxt;
  }
  float vz = (j < 15) ? (alpha + end_t[j]) : -3.0e38f;
  float mz = vz;
  #pragma unroll
  for (int off = 32; off > 0; off >>= 1) mz = fmaxf(mz, __shfl_xor(mz, off, 64));
  float se = (j < 15) ? __expf(vz - mz) : 0.f;
  #pragma unroll
  for (int off = 32; off > 0; off >>= 1) se += __shfl_xor(se, off, 64);
  const float logZ = mz + __logf(se);

  float sc = 0.f; int cnt = 0;
  for (int s = j; s < 512; s += 64) cnt += (mks[s] ? 1 : 0);
  for (int s = 1 + j; s < 512; s += 64) {
    if (mks[s]) {
      const int tp = tgs[s-1], tc = tgs[s];
      sc += trs[tp*15 + tc] + ems[s*15 + tc];
    }
  }
  #pragma unroll
  for (int off = 32; off > 0; off >>= 1) {
    sc  += __shfl_xor(sc, off, 64);
    cnt += __shfl_xor(cnt, off, 64);
  }
  if (j == 0) {
    const int t0 = tgs[0];
    sc += start_t[t0] + ems[t0];
    int last = cnt - 1; if (last < 0) last = 0;
    sc += end_t[tgs[last]];
    nllb[b] = logZ - sc;
  }
}

__global__ __launch_bounds__(64) void nll_reduce_kernel(const float* __restrict__ nllb,
                                                        float* __restrict__ out) {
  const int j = threadIdx.x;
  float v = (j < 32) ? nllb[j] : 0.f;
  #pragma unroll
  for (int off = 32; off > 0; off >>= 1) v += __shfl_xor(v, off, 64);
  if (j == 0) out[0] = v;
}

// ---------------- launch ----------------
extern "C" void kernel_launch(void* const* d_in, const int* in_sizes, int n_in,
                              void* d_out, int out_size, void* d_ws, size_t ws_size,
                              hipStream_t stream) {
  const float* x      = (const float*)d_in[0];
  const int*   tags   = (const int*)d_in[1];
  const int*   mask   = (const int*)d_in[2];
  const float* Wih_f  = (const float*)d_in[3];
  const float* Whh_f  = (const float*)d_in[4];
  const float* bih_f  = (const float*)d_in[5];
  const float* bhh_f  = (const float*)d_in[6];
  const float* Wih_b  = (const float*)d_in[7];
  const float* Whh_b  = (const float*)d_in[8];
  const float* bih_b  = (const float*)d_in[9];
  const float* bhh_b  = (const float*)d_in[10];
  const float* Wp     = (const float*)d_in[11];
  const float* bp     = (const float*)d_in[12];
  const float* trans  = (const float*)d_in[13];
  const float* start_t= (const float*)d_in[14];
  const float* end_t  = (const float*)d_in[15];
  float* out = (float*)d_out;

  char* ws = (char*)d_ws;
  size_t off = 0;
  auto alloc = [&](size_t bytes) { char* p = ws + off; off += (bytes + 255) & ~(size_t)255; return p; };
  __hip_bfloat16* xbf   = (__hip_bfloat16*)alloc((size_t)NM*NE*2);        // 25.2 MB
  __hip_bfloat16* Wihbf = (__hip_bfloat16*)alloc((size_t)1024*NE*2);      // 1.6 MB
  __hip_bfloat16* whhp  = (__hip_bfloat16*)alloc((size_t)2*512*128*2);    // 0.26 MB
  float*          biasp = (float*)alloc(1024*4);
  __hip_bfloat16* xqd   = (__hip_bfloat16*)alloc((size_t)2*NM*512*2);     // 33.6 MB
  unsigned short* hf    = (unsigned short*)alloc((size_t)NM*128*2);       // 4.2 MB
  unsigned short* hb    = (unsigned short*)alloc((size_t)NM*128*2);       // 4.2 MB
  float*          em    = (float*)alloc((size_t)NM*15*4);                 // 1.0 MB
  float*          nllb  = (float*)alloc(32*4);
  (void)ws_size; (void)in_sizes; (void)n_in; (void)out_size;

  cvt_bf16_kernel<<<2048, 256, 0, stream>>>(x, xbf, NM*NE/4);
  prep_weights_kernel<<<1024, 256, 0, stream>>>(Wih_f, Wih_b, Whh_f, Whh_b,
                                                bih_f, bhh_f, bih_b, bhh_b,
                                                Wihbf, whhp, biasp);

  gemm_xproj<<<dim3(128, 8), 256, 0, stream>>>(xbf, Wihbf, biasp, xqd);
  lstm_mfma<<<16, 512, 0, stream>>>(xqd, whhp, hf, hb);
  em_kernel<<<128, 128, 0, stream>>>(hf, hb, Wp, bp, em);
  crf_kernel<<<32, 64, 0, stream>>>(em, tags, mask, trans, start_t, end_t, nllb);
  nll_reduce_kernel<<<1, 64, 0, stream>>>(nllb, out);
}

// Round 17
// 503.457 us; speedup vs baseline: 1.2059x; 1.1722x over previous
//
#include <hip/hip_runtime.h>
#include <hip/hip_bf16.h>
#include <cstdint>

typedef __attribute__((ext_vector_type(8))) short short8;
typedef __attribute__((ext_vector_type(4))) float f32x4;

#define NS 512
#define NB 32
#define NE 768
#define NH 128
#define NT 15
#define NM (NB*NS)      // 16384 rows, m = b*512 + s

#define LOG2E  1.4426950408889634f
#define LOG2E2 2.8853900817779268f

__device__ __forceinline__ float bflo(unsigned int u){ return __builtin_bit_cast(float, u << 16); }
__device__ __forceinline__ float bfhi(unsigned int u){ return __builtin_bit_cast(float, u & 0xffff0000u); }
__device__ __forceinline__ float bfu(unsigned short u){ return __builtin_bit_cast(float, (unsigned)u << 16); }

__device__ __forceinline__ float rcpf_(float x){
#if __has_builtin(__builtin_amdgcn_rcpf)
  return __builtin_amdgcn_rcpf(x);
#else
  return __fdividef(1.f, x);
#endif
}
__device__ __forceinline__ float ex2_(float x){
#if __has_builtin(__builtin_amdgcn_exp2f)
  return __builtin_amdgcn_exp2f(x);
#else
  return exp2f(x);
#endif
}

// raw workgroup barrier: LDS-drain only, global loads/stores stay in flight.
__device__ __forceinline__ void lds_barrier() {
  asm volatile("s_waitcnt lgkmcnt(0)" ::: "memory");
  __builtin_amdgcn_s_barrier();
  asm volatile("" ::: "memory");
}

__device__ __forceinline__ void gload16(const void* g, void* l) {
#if __has_builtin(__builtin_amdgcn_global_load_lds)
  __builtin_amdgcn_global_load_lds((const __attribute__((address_space(1))) void*)g,
                                   (__attribute__((address_space(3))) void*)l, 16, 0, 0);
#else
  *(uint4*)l = *(const uint4*)g;
#endif
}

__device__ __forceinline__ float rdlane(float v, int i){
#if __has_builtin(__builtin_amdgcn_readlane)
  return __builtin_bit_cast(float, __builtin_amdgcn_readlane(__builtin_bit_cast(int, v), i));
#else
  return __shfl(v, i, 64);
#endif
}

// ---------------- converts ----------------
__global__ void cvt_bf16_kernel(const float* __restrict__ in,
                                __hip_bfloat16* __restrict__ out, int n4) {
  int i = blockIdx.x*blockDim.x + threadIdx.x;
  int stride = gridDim.x*blockDim.x;
  for (int j = i; j < n4; j += stride) {
    float4 v = ((const float4*)in)[j];
    ushort4 o;
    o.x = __builtin_bit_cast(unsigned short, __float2bfloat16(v.x));
    o.y = __builtin_bit_cast(unsigned short, __float2bfloat16(v.y));
    o.z = __builtin_bit_cast(unsigned short, __float2bfloat16(v.z));
    o.w = __builtin_bit_cast(unsigned short, __float2bfloat16(v.w));
    ((ushort4*)out)[j] = o;
  }
}

// Fused weight prep: one block per permuted row n = dir*512 + (j*4+g).
// Scale: log2e for gates i,f,o; 2*log2e for g -> activations use exp2 directly.
__global__ void prep_weights_kernel(
    const float* __restrict__ wihf, const float* __restrict__ wihb,
    const float* __restrict__ whhf, const float* __restrict__ whhb,
    const float* __restrict__ bihf, const float* __restrict__ bhhf,
    const float* __restrict__ bihb, const float* __restrict__ bhhb,
    __hip_bfloat16* __restrict__ wihp,   // [1024][768]
    __hip_bfloat16* __restrict__ whhp,   // [1024][128]
    float* __restrict__ biasp)           // [1024]
{
  const int n = blockIdx.x;           // 0..1023
  const int dir = n >> 9, cc = n & 511, j = cc >> 2, g = cc & 3;
  const float fac = (g == 2) ? LOG2E2 : LOG2E;
  const int srow = g*128 + j;
  const float* si = (dir ? wihb : wihf) + (size_t)srow*768;
  __hip_bfloat16* di = wihp + (size_t)n*768;
  for (int e = threadIdx.x; e < 768; e += 256) di[e] = __float2bfloat16(si[e]*fac);
  const float* sh = (dir ? whhb : whhf) + (size_t)srow*128;
  __hip_bfloat16* dh = whhp + (size_t)n*128;
  if (threadIdx.x < 128) dh[threadIdx.x] = __float2bfloat16(sh[threadIdx.x]*fac);
  if (threadIdx.x == 0)
    biasp[n] = fac * (dir ? (bihb[srow] + bhhb[srow]) : (bihf[srow] + bhhf[srow]));
}

// ---------------- xproj GEMM: A[16384x768] @ Bw[1024x768]^T -> xqd[2][NM][512] ----------------
// 1D grid 1024 blocks, 4/CU; bijective XCD swizzle (nwg%8==0) + row-major block
// order so each XCD's contiguous chunk shares A panels (L2 locality).
__global__ __launch_bounds__(256, 4) void gemm_xproj(
    const __hip_bfloat16* __restrict__ A,
    const __hip_bfloat16* __restrict__ Bw,
    const float* __restrict__ biasp,
    __hip_bfloat16* __restrict__ xqd)        // [2][NM][512] packed j*4+g, scaled
{
  __shared__ __align__(16) __hip_bfloat16 As[128*64];
  __shared__ __align__(16) __hip_bfloat16 Bs[128*64];
  const int id  = blockIdx.x;
  const int swz = (id & 7)*128 + (id >> 3);   // bijective: 1024 = 8 XCD x 128
  const int bm = (swz >> 3) * 128;
  const int bn = (swz & 7) * 128;
  const int tid = threadIdx.x;
  const int lane = tid & 63;
  const int wv = tid >> 6;
  const int wr = wv >> 1, wc = wv & 1;
  char* AsB = (char*)As;
  char* BsB = (char*)Bs;
  const char* Ab = (const char*)A;
  const char* Bb = (const char*)Bw;
  f32x4 acc[4][4] = {};

  for (int kt = 0; kt < 12; ++kt) {
    const int k0 = kt * 64;
    __syncthreads();
    #pragma unroll
    for (int i = 0; i < 4; ++i) {
      int fb = i*4096 + tid*16;
      int r  = fb >> 7;
      int cb = fb & 127;
      gload16(Ab + ((size_t)(bm + r)*768 + k0)*2 + cb, AsB + fb);
      gload16(Bb + ((size_t)(bn + r)*768 + k0)*2 + cb, BsB + fb);
    }
    __syncthreads();
    #pragma unroll
    for (int ks = 0; ks < 2; ++ks) {
      const int krow = ks*32 + ((lane >> 4) << 3);
      short8 af[4], bfr[4];
      #pragma unroll
      for (int m = 0; m < 4; ++m) {
        int row = wr*64 + m*16 + (lane & 15);
        af[m] = *(const short8*)(AsB + (row*64 + krow)*2);
      }
      #pragma unroll
      for (int n = 0; n < 4; ++n) {
        int row = wc*64 + n*16 + (lane & 15);
        bfr[n] = *(const short8*)(BsB + (row*64 + krow)*2);
      }
      #pragma unroll
      for (int m = 0; m < 4; ++m)
        #pragma unroll
        for (int n = 0; n < 4; ++n)
          acc[m][n] = __builtin_amdgcn_mfma_f32_16x16x32_bf16(af[m], bfr[n], acc[m][n], 0, 0, 0);
    }
  }
  #pragma unroll
  for (int m = 0; m < 4; ++m) {
    #pragma unroll
    for (int n = 0; n < 4; ++n) {
      const int col = bn + wc*64 + n*16 + (lane & 15);
      const float bv = biasp[col];
      const int dir = col >> 9;
      const int cc  = col & 511;
      #pragma unroll
      for (int jj = 0; jj < 4; ++jj) {
        const int row = bm + wr*64 + m*16 + ((lane >> 4)*4 + jj);
        xqd[((size_t)dir*NM + row)*512 + cc] = __float2bfloat16(acc[m][n][jj] + bv);
      }
    }
  }
}

// ---------------- LSTM: frozen R15 structure (two-phase, refill-after-consume) ----------------
__global__ __launch_bounds__(512) __attribute__((amdgpu_waves_per_eu(1, 2)))
void lstm_mfma(
    const __hip_bfloat16* __restrict__ xqd,   // [2][NM][512] packed j*4+g, bias folded, scaled
    const __hip_bfloat16* __restrict__ whhp,  // [2][512][128] permuted rows, scaled
    unsigned short* __restrict__ hf,          // [NM][128] bf16
    unsigned short* __restrict__ hb)          // [NM][128] bf16
{
  __shared__ __align__(16) char hfrag[2*4224];   // [buf][kc:1056B][lane:16B] B-frag layout
  __shared__ __align__(16) float z_lds[4*520];   // [b][4*swz(j)] f32x4, swizzled

  const int bid = blockIdx.x;
  const int dir = bid >> 3, bg = bid & 7;
  const int t = threadIdx.x;
  const int w = t >> 6, l = t & 63;
  const int ln = l & 15, lp = l >> 4;

  // A-fragments (weights): wave w rows (w*4+r)*16+ln, k = kc*32 + lp*8 + e.
  uint4 afu[4][4];
  {
    const char* wbase = (const char*)(whhp + (size_t)dir*512*128);
    #pragma unroll
    for (int r = 0; r < 4; ++r) {
      const int row = (w*4 + r)*16 + ln;
      #pragma unroll
      for (int kc = 0; kc < 4; ++kc)
        afu[r][kc] = *(const uint4*)(wbase + ((size_t)row*128 + lp*8 + kc*32)*2);
    }
  }

  for (int i = t; i < 2*4224/4; i += 512) ((int*)hfrag)[i] = 0;

  // phase-B identity
  const int b4 = t & 3, j = t >> 2;
  const int bsafe = bg*4 + b4;
  const int jsw = j ^ ((j >> 3) & 7);
  const int woff = (j >> 5)*1056 + ((j >> 3) & 3)*256 + b4*16 + (j & 7)*2;
  const int sdir = dir ? -1 : 1;
  const int s0 = dir ? 511 : 0;
  const ptrdiff_t xstep = (ptrdiff_t)sdir*512;
  const ptrdiff_t hstep = (ptrdiff_t)sdir*128;
  const __hip_bfloat16* xbase = xqd + ((size_t)dir*NM + (size_t)bsafe*512)*512
                                + (ptrdiff_t)s0*512 + j*4;
  unsigned short* hout = (dir ? hb : hf) + (size_t)bsafe*512*128 + (ptrdiff_t)s0*128 + j;

  float c = 0.f;

  // depth-4 x ring
  uint2 x0 = *(const uint2*)(xbase);
  uint2 x1 = *(const uint2*)(xbase + xstep);
  uint2 x2 = *(const uint2*)(xbase + 2*xstep);
  uint2 x3 = *(const uint2*)(xbase + 3*xstep);
  const __hip_bfloat16* xpre = xbase + 4*xstep;   // next address to fetch
  __syncthreads();   // prologue only

  int buf = 0;

  auto STEP = [&](uint2& xc, bool pf) {
    // ---- phase A: B-fragments (lane-linear, conflict-free) + 16 MFMA ----
    short8 bfv[4];
    #pragma unroll
    for (int kc = 0; kc < 4; ++kc)
      bfv[kc] = *(const short8*)(hfrag + buf*4224 + kc*1056 + l*16);

    f32x4 acc[4];
    #pragma unroll
    for (int r = 0; r < 4; ++r) {
      acc[r] = f32x4{0.f, 0.f, 0.f, 0.f};
      #pragma unroll
      for (int kc = 0; kc < 4; ++kc)
        acc[r] = __builtin_amdgcn_mfma_f32_16x16x32_bf16(
                   __builtin_bit_cast(short8, afu[r][kc]), bfv[kc], acc[r], 0, 0, 0);
    }

    // publish z (real batch cols ln<4 only), XOR-swizzled -> conflict-free
    if (ln < 4) {
      #pragma unroll
      for (int r = 0; r < 4; ++r) {
        const int jw = (w*4 + r)*4 + lp;
        const int js = jw ^ ((jw >> 3) & 7);
        *(f32x4*)&z_lds[ln*520 + 4*js] = acc[r];
      }
    }
    lds_barrier();

    // ---- phase B: one h per thread (exp2 forms, inputs pre-scaled) ----
    const f32x4 zv = *(const f32x4*)&z_lds[b4*520 + 4*jsw];
    const float zi = zv[0] + bflo(xc.x);
    const float zf = zv[1] + bfhi(xc.x);
    const float zg = zv[2] + bflo(xc.y);
    const float zo = zv[3] + bfhi(xc.y);
    const float I = rcpf_(1.f + ex2_(-zi));
    const float F = rcpf_(1.f + ex2_(-zf));
    const float G = 1.f - 2.f*rcpf_(ex2_(zg) + 1.f);
    const float O = rcpf_(1.f + ex2_(-zo));
    c = F*c + I*G;
    const float h = O*(1.f - 2.f*rcpf_(ex2_(c*LOG2E2) + 1.f));

    const unsigned short hbits =
        __builtin_bit_cast(unsigned short, __float2bfloat16(h));
    *(short*)(hfrag + (buf ^ 1)*4224 + woff) = (short)hbits;
    *hout = hbits;                     // fire-and-forget bf16 store
    hout += hstep;

    // refill AFTER consume: load directly into xc's register
    if (pf) { xc = *(const uint2*)xpre; xpre += xstep; }
    lds_barrier();
    buf ^= 1;
  };

  for (int it = 0; it < 127; ++it) {   // 508 steps with prefetch
    // AGPR pin (R9-proven residency mechanism)
    #pragma unroll
    for (int r = 0; r < 4; ++r)
      #pragma unroll
      for (int kc = 0; kc < 4; ++kc)
        asm volatile("" : "+a"(afu[r][kc].x), "+a"(afu[r][kc].y),
                          "+a"(afu[r][kc].z), "+a"(afu[r][kc].w));
    STEP(x0, true);
    STEP(x1, true);
    STEP(x2, true);
    STEP(x3, true);
  }
  // epilogue: last 4 steps, no prefetch
  STEP(x0, false);
  STEP(x1, false);
  STEP(x2, false);
  STEP(x3, false);
}

// ---------------- emissions: em[m][t] = [hf|hb][m] . Wp[t] + bp[t]  (bf16 h) ----------------
__global__ __launch_bounds__(128) void em_kernel(
    const unsigned short* __restrict__ hf, const unsigned short* __restrict__ hb,
    const float* __restrict__ Wp, const float* __restrict__ bp,
    float* __restrict__ em)
{
  __shared__ float wps[15*256];
  __shared__ float bps[15];
  const int tid = threadIdx.x;
  for (int i = tid; i < 15*256; i += 128) wps[i] = Wp[i];
  if (tid < 15) bps[tid] = bp[tid];
  __syncthreads();
  const size_t m = (size_t)blockIdx.x*128 + tid;
  float acc[15];
  #pragma unroll
  for (int t2 = 0; t2 < 15; ++t2) acc[t2] = bps[t2];
  const ushort4* hf4 = (const ushort4*)(hf + m*128);
  const ushort4* hb4 = (const ushort4*)(hb + m*128);
  for (int kc = 0; kc < 32; ++kc) {
    const ushort4 hv = hf4[kc];
    const float h0 = bfu(hv.x), h1 = bfu(hv.y), h2 = bfu(hv.z), h3 = bfu(hv.w);
    #pragma unroll
    for (int t2 = 0; t2 < 15; ++t2)
      acc[t2] += h0*wps[t2*256 + kc*4+0] + h1*wps[t2*256 + kc*4+1]
               + h2*wps[t2*256 + kc*4+2] + h3*wps[t2*256 + kc*4+3];
  }
  for (int kc = 0; kc < 32; ++kc) {
    const ushort4 hv = hb4[kc];
    const float h0 = bfu(hv.x), h1 = bfu(hv.y), h2 = bfu(hv.z), h3 = bfu(hv.w);
    #pragma unroll
    for (int t2 = 0; t2 < 15; ++t2)
      acc[t2] += h0*wps[t2*256 + 128 + kc*4+0] + h1*wps[t2*256 + 128 + kc*4+1]
               + h2*wps[t2*256 + 128 + kc*4+2] + h3*wps[t2*256 + 128 + kc*4+3];
  }
  float* eo = em + m*15;
  #pragma unroll
  for (int t2 = 0; t2 < 15; ++t2) eo[t2] = acc[t2];
}

// ---------------- CRF chunk scan: per-(batch, chunk-of-16-steps) transfer matrix ----------------
// Semiring (LSE,+): M_s[i][j] = trans[i][j] + em[s][j]; masked step -> identity.
// P_c = M_{s0} x ... (s0 = 1+16c). new[i][j] = em[s][j] + LSE_k(cur[i][k]+trans[k][j]).
__global__ __launch_bounds__(64) void crf_chunks(
    const float* __restrict__ em,    // [32][512][15]
    const int* __restrict__ mask,    // [32][512]
    const float* __restrict__ trans, // [15][15]
    float* __restrict__ pmat)        // [32][32][240] (15x16 padded)
{
  __shared__ float trs[240];         // [k][j] padded stride 16
  __shared__ float cur[2][15][16];
  __shared__ float emc[16][16];
  __shared__ int mkc[16];
  const int b = blockIdx.x, cix = blockIdx.y;
  const int t = threadIdx.x;
  const int s0 = 1 + cix*16;
  const int ns = (512 - s0 < 16) ? (512 - s0) : 16;

  for (int e = t; e < 225; e += 64) trs[(e/15)*16 + (e%15)] = trans[e];
  for (int e = t; e < ns*15; e += 64) {
    const int k = e/15, j = e%15;
    emc[k][j] = em[((size_t)b*512 + s0 + k)*15 + j];
  }
  if (t < ns) mkc[t] = mask[b*512 + s0 + t];
  for (int e = t; e < 225; e += 64) {
    const int i = e/15, j = e%15;
    cur[0][i][j] = (i == j) ? 0.f : -1e30f;
  }
  __syncthreads();

  int cb = 0;
  for (int k = 0; k < ns; ++k) {
    if (mkc[k]) {                    // uniform branch (LDS value, same for all)
      for (int e = t; e < 225; e += 64) {
        const int i = e/15, j = e%15;
        float v[15];
        #pragma unroll
        for (int k2 = 0; k2 < 15; ++k2) v[k2] = cur[cb][i][k2] + trs[k2*16 + j];
        const float a01 = fmaxf(v[0], v[1]),  a23 = fmaxf(v[2], v[3]);
        const float a45 = fmaxf(v[4], v[5]),  a67 = fmaxf(v[6], v[7]);
        const float a89 = fmaxf(v[8], v[9]),  aab = fmaxf(v[10], v[11]);
        const float acd = fmaxf(v[12], v[13]);
        const float q0 = fmaxf(a01, a23), q1 = fmaxf(a45, a67);
        const float q2 = fmaxf(a89, aab), q3 = fmaxf(acd, v[14]);
        const float mx = fmaxf(fmaxf(q0, q1), fmaxf(q2, q3));
        float sum = 0.f;
        #pragma unroll
        for (int k2 = 0; k2 < 15; ++k2) sum += __expf(v[k2] - mx);
        cur[cb ^ 1][i][j] = emc[k][j] + mx + __logf(sum);
      }
      __syncthreads();
      cb ^= 1;
    }
  }
  float* P = pmat + ((size_t)b*32 + cix)*240;
  for (int e = t; e < 225; e += 64) {
    const int i = e/15, j = e%15;
    P[i*16 + j] = cur[cb][i][j];
  }
}

// ---------------- CRF final: alpha0 x P_0..P_31, logZ, gold score ----------------
__global__ __launch_bounds__(64) void crf_final(
    const float* __restrict__ em,
    const float* __restrict__ pmat,  // [32][32][240]
    const int* __restrict__ tags, const int* __restrict__ mask,
    const float* __restrict__ trans, const float* __restrict__ start_t,
    const float* __restrict__ end_t, float* __restrict__ nllb)
{
  __shared__ __align__(16) float ems[512*15];
  __shared__ float trs[225];
  __shared__ float Pl[240];
  __shared__ int tgs[512];
  __shared__ int mks[512];
  const int b = blockIdx.x, j = threadIdx.x;
  const float* emb = em + (size_t)b*512*15;
  {
    const float4* s4 = (const float4*)emb;
    float4* d4 = (float4*)ems;
    for (int i = j; i < 512*15/4; i += 64) d4[i] = s4[i];
    for (int i = j; i < 512; i += 64) { tgs[i] = tags[b*512+i]; mks[i] = mask[b*512+i]; }
    for (int i = j; i < 225; i += 64) trs[i] = trans[i];
  }
  __syncthreads();

  const int jc = (j < 15) ? j : 0;
  float alpha = (j < 15) ? (start_t[j] + ems[j]) : -1e30f;
  for (int cix = 0; cix < 32; ++cix) {
    const float* P = pmat + ((size_t)b*32 + cix)*240;
    __syncthreads();
    for (int e = j; e < 240; e += 64) Pl[e] = P[e];
    __syncthreads();
    float v[15];
    #pragma unroll
    for (int i = 0; i < 15; ++i) {
      const float ai = rdlane(alpha, i);
      v[i] = ai + Pl[i*16 + jc];
    }
    const float a01 = fmaxf(v[0], v[1]),  a23 = fmaxf(v[2], v[3]);
    const float a45 = fmaxf(v[4], v[5]),  a67 = fmaxf(v[6], v[7]);
    const float a89 = fmaxf(v[8], v[9]),  aab = fmaxf(v[10], v[11]);
    const float acd = fmaxf(v[12], v[13]);
    const float q0 = fmaxf(a01, a23), q1 = fmaxf(a45, a67);
    const float q2 = fmaxf(a89, aab), q3 = fmaxf(acd, v[14]);
    const float mx = fmaxf(fmaxf(q0, q1), fmaxf(q2, q3));
    float sum = 0.f;
    #pragma unroll
    for (int i = 0; i < 15; ++i) sum += __expf(v[i] - mx);
    const float nxt = mx + __logf(sum);
    if (j < 15) alpha = nxt;
  }

  float vz = (j < 15) ? (alpha + end_t[j]) : -1e30f;
  float mz = vz;
  #pragma unroll
  for (int off = 32; off > 0; off >>= 1) mz = fmaxf(mz, __shfl_xor(mz, off, 64));
  float se = (j < 15) ? __expf(vz - mz) : 0.f;
  #pragma unroll
  for (int off = 32; off > 0; off >>= 1) se += __shfl_xor(se, off, 64);
  const float logZ = mz + __logf(se);

  float sc = 0.f; int cnt = 0;
  for (int s = j; s < 512; s += 64) cnt += (mks[s] ? 1 : 0);
  for (int s = 1 + j; s < 512; s += 64) {
    if (mks[s]) {
      const int tp = tgs[s-1], tc = tgs[s];
      sc += trs[tp*15 + tc] + ems[s*15 + tc];
    }
  }
  #pragma unroll
  for (int off = 32; off > 0; off >>= 1) {
    sc  += __shfl_xor(sc, off, 64);
    cnt += __shfl_xor(cnt, off, 64);
  }
  if (j == 0) {
    const int t0 = tgs[0];
    sc += start_t[t0] + ems[t0];
    int last = cnt - 1; if (last < 0) last = 0;
    sc += end_t[tgs[last]];
    nllb[b] = logZ - sc;
  }
}

__global__ __launch_bounds__(64) void nll_reduce_kernel(const float* __restrict__ nllb,
                                                        float* __restrict__ out) {
  const int j = threadIdx.x;
  float v = (j < 32) ? nllb[j] : 0.f;
  #pragma unroll
  for (int off = 32; off > 0; off >>= 1) v += __shfl_xor(v, off, 64);
  if (j == 0) out[0] = v;
}

// ---------------- launch ----------------
extern "C" void kernel_launch(void* const* d_in, const int* in_sizes, int n_in,
                              void* d_out, int out_size, void* d_ws, size_t ws_size,
                              hipStream_t stream) {
  const float* x      = (const float*)d_in[0];
  const int*   tags   = (const int*)d_in[1];
  const int*   mask   = (const int*)d_in[2];
  const float* Wih_f  = (const float*)d_in[3];
  const float* Whh_f  = (const float*)d_in[4];
  const float* bih_f  = (const float*)d_in[5];
  const float* bhh_f  = (const float*)d_in[6];
  const float* Wih_b  = (const float*)d_in[7];
  const float* Whh_b  = (const float*)d_in[8];
  const float* bih_b  = (const float*)d_in[9];
  const float* bhh_b  = (const float*)d_in[10];
  const float* Wp     = (const float*)d_in[11];
  const float* bp     = (const float*)d_in[12];
  const float* trans  = (const float*)d_in[13];
  const float* start_t= (const float*)d_in[14];
  const float* end_t  = (const float*)d_in[15];
  float* out = (float*)d_out;

  char* ws = (char*)d_ws;
  size_t off = 0;
  auto alloc = [&](size_t bytes) { char* p = ws + off; off += (bytes + 255) & ~(size_t)255; return p; };
  __hip_bfloat16* xbf   = (__hip_bfloat16*)alloc((size_t)NM*NE*2);        // 25.2 MB
  __hip_bfloat16* Wihbf = (__hip_bfloat16*)alloc((size_t)1024*NE*2);      // 1.6 MB
  __hip_bfloat16* whhp  = (__hip_bfloat16*)alloc((size_t)2*512*128*2);    // 0.26 MB
  float*          biasp = (float*)alloc(1024*4);
  __hip_bfloat16* xqd   = (__hip_bfloat16*)alloc((size_t)2*NM*512*2);     // 33.6 MB
  unsigned short* hf    = (unsigned short*)alloc((size_t)NM*128*2);       // 4.2 MB
  unsigned short* hb    = (unsigned short*)alloc((size_t)NM*128*2);       // 4.2 MB
  float*          em    = (float*)alloc((size_t)NM*15*4);                 // 1.0 MB
  float*          pmat  = (float*)alloc((size_t)32*32*240*4);             // 1.0 MB
  float*          nllb  = (float*)alloc(32*4);
  (void)ws_size; (void)in_sizes; (void)n_in; (void)out_size;

  cvt_bf16_kernel<<<2048, 256, 0, stream>>>(x, xbf, NM*NE/4);
  prep_weights_kernel<<<1024, 256, 0, stream>>>(Wih_f, Wih_b, Whh_f, Whh_b,
                                                bih_f, bhh_f, bih_b, bhh_b,
                                                Wihbf, whhp, biasp);

  gemm_xproj<<<1024, 256, 0, stream>>>(xbf, Wihbf, biasp, xqd);
  lstm_mfma<<<16, 512, 0, stream>>>(xqd, whhp, hf, hb);
  em_kernel<<<128, 128, 0, stream>>>(hf, hb, Wp, bp, em);
  crf_chunks<<<dim3(32, 32), 64, 0, stream>>>(em, mask, trans, pmat);
  crf_final<<<32, 64, 0, stream>>>(em, pmat, tags, mask, trans, start_t, end_t, nllb);
  nll_reduce_kernel<<<1, 64, 0, stream>>>(nllb, out);
}

// Round 18
// 495.272 us; speedup vs baseline: 1.2258x; 1.0165x over previous
//
#include <hip/hip_runtime.h>
#include <hip/hip_bf16.h>
#include <cstdint>

typedef __attribute__((ext_vector_type(8))) short short8;
typedef __attribute__((ext_vector_type(4))) float f32x4;

#define NS 512
#define NB 32
#define NE 768
#define NH 128
#define NT 15
#define NM (NB*NS)      // 16384 rows, m = b*512 + s

#define LOG2E  1.4426950408889634f
#define LOG2E2 2.8853900817779268f

__device__ __forceinline__ float bflo(unsigned int u){ return __builtin_bit_cast(float, u << 16); }
__device__ __forceinline__ float bfhi(unsigned int u){ return __builtin_bit_cast(float, u & 0xffff0000u); }
__device__ __forceinline__ float bfu(unsigned short u){ return __builtin_bit_cast(float, (unsigned)u << 16); }

__device__ __forceinline__ float rcpf_(float x){
#if __has_builtin(__builtin_amdgcn_rcpf)
  return __builtin_amdgcn_rcpf(x);
#else
  return __fdividef(1.f, x);
#endif
}
__device__ __forceinline__ float ex2_(float x){
#if __has_builtin(__builtin_amdgcn_exp2f)
  return __builtin_amdgcn_exp2f(x);
#else
  return exp2f(x);
#endif
}

// raw workgroup barrier: LDS-drain only, global loads/stores stay in flight.
__device__ __forceinline__ void lds_barrier() {
  asm volatile("s_waitcnt lgkmcnt(0)" ::: "memory");
  __builtin_amdgcn_s_barrier();
  asm volatile("" ::: "memory");
}

__device__ __forceinline__ void gload16(const void* g, void* l) {
#if __has_builtin(__builtin_amdgcn_global_load_lds)
  __builtin_amdgcn_global_load_lds((const __attribute__((address_space(1))) void*)g,
                                   (__attribute__((address_space(3))) void*)l, 16, 0, 0);
#else
  *(uint4*)l = *(const uint4*)g;
#endif
}

__device__ __forceinline__ float rdlane(float v, int i){
#if __has_builtin(__builtin_amdgcn_readlane)
  return __builtin_bit_cast(float, __builtin_amdgcn_readlane(__builtin_bit_cast(int, v), i));
#else
  return __shfl(v, i, 64);
#endif
}

// ---------------- fused prep: x->bf16 convert (blocks 0..2047) + weight prep (2048..3071) ----------------
// Weight scale: log2e for gates i,f,o; 2*log2e for g -> activations use exp2 directly.
__global__ void prep_all_kernel(
    const float* __restrict__ x,
    const float* __restrict__ wihf, const float* __restrict__ wihb,
    const float* __restrict__ whhf, const float* __restrict__ whhb,
    const float* __restrict__ bihf, const float* __restrict__ bhhf,
    const float* __restrict__ bihb, const float* __restrict__ bhhb,
    __hip_bfloat16* __restrict__ xbf,    // [NM][768]
    __hip_bfloat16* __restrict__ wihp,   // [1024][768]
    __hip_bfloat16* __restrict__ whhp,   // [1024][128]
    float* __restrict__ biasp)           // [1024]
{
  const int blk = blockIdx.x;
  if (blk < 2048) {
    const int n4 = NM*NE/4;
    int i = blk*256 + threadIdx.x;
    int stride = 2048*256;
    for (int j = i; j < n4; j += stride) {
      float4 v = ((const float4*)x)[j];
      ushort4 o;
      o.x = __builtin_bit_cast(unsigned short, __float2bfloat16(v.x));
      o.y = __builtin_bit_cast(unsigned short, __float2bfloat16(v.y));
      o.z = __builtin_bit_cast(unsigned short, __float2bfloat16(v.z));
      o.w = __builtin_bit_cast(unsigned short, __float2bfloat16(v.w));
      ((ushort4*)xbf)[j] = o;
    }
  } else {
    const int n = blk - 2048;         // 0..1023, permuted row = dir*512 + (j*4+g)
    const int dir = n >> 9, cc = n & 511, j = cc >> 2, g = cc & 3;
    const float fac = (g == 2) ? LOG2E2 : LOG2E;
    const int srow = g*128 + j;
    const float* si = (dir ? wihb : wihf) + (size_t)srow*768;
    __hip_bfloat16* di = wihp + (size_t)n*768;
    for (int e = threadIdx.x; e < 768; e += 256) di[e] = __float2bfloat16(si[e]*fac);
    const float* sh = (dir ? whhb : whhf) + (size_t)srow*128;
    __hip_bfloat16* dh = whhp + (size_t)n*128;
    if (threadIdx.x < 128) dh[threadIdx.x] = __float2bfloat16(sh[threadIdx.x]*fac);
    if (threadIdx.x == 0)
      biasp[n] = fac * (dir ? (bihb[srow] + bhhb[srow]) : (bihf[srow] + bhhf[srow]));
  }
}

// ---------------- xproj GEMM: A[16384x768] @ Bw[1024x768]^T -> xqd[2][NM][512] ----------------
// 1024 blocks (4/CU), bijective XCD swizzle. T2 both-sides XOR swizzle on LDS
// (rule #21): linear gload_lds dest + pre-swizzled global SOURCE (16B units
// permute within each 128B row -> same cache lines, coalescing kept) +
// swizzled ds_read addr. Kills the row-stride-128B 16-way bank conflict.
__global__ __launch_bounds__(256, 4) void gemm_xproj(
    const __hip_bfloat16* __restrict__ A,
    const __hip_bfloat16* __restrict__ Bw,
    const float* __restrict__ biasp,
    __hip_bfloat16* __restrict__ xqd)        // [2][NM][512] packed j*4+g, scaled
{
  __shared__ __align__(16) __hip_bfloat16 As[128*64];
  __shared__ __align__(16) __hip_bfloat16 Bs[128*64];
  const int id  = blockIdx.x;
  const int swzb = (id & 7)*128 + (id >> 3);   // bijective: 1024 = 8 XCD x 128
  const int bm = (swzb >> 3) * 128;
  const int bn = (swzb & 7) * 128;
  const int tid = threadIdx.x;
  const int lane = tid & 63;
  const int wv = tid >> 6;
  const int wr = wv >> 1, wc = wv & 1;
  char* AsB = (char*)As;
  char* BsB = (char*)Bs;
  const char* Ab = (const char*)A;
  const char* Bb = (const char*)Bw;
  f32x4 acc[4][4] = {};

  for (int kt = 0; kt < 12; ++kt) {
    const int k0 = kt * 64;
    __syncthreads();
    #pragma unroll
    for (int i = 0; i < 4; ++i) {
      int fb = i*4096 + tid*16;       // linear LDS dest (gload_lds requirement)
      int r  = fb >> 7;               // row (128B per row of 64 bf16)
      int cb = fb & 127;
      int cbs = cb ^ ((r & 7) << 4);  // pre-swizzled SOURCE: LDS[r][u] = G[r][u^(r&7)]
      gload16(Ab + ((size_t)(bm + r)*768 + k0)*2 + cbs, AsB + fb);
      gload16(Bb + ((size_t)(bn + r)*768 + k0)*2 + cbs, BsB + fb);
    }
    __syncthreads();
    const int sw = ((lane & 7) << 4); // row&7 == ln&7 for all fragment rows
    #pragma unroll
    for (int ks = 0; ks < 2; ++ks) {
      const int krowb = ks*64 + ((lane >> 4) << 4);   // byte offset of k-slice
      const int krows = krowb ^ sw;                    // swizzled read -> 2-way banks
      short8 af[4], bfr[4];
      #pragma unroll
      for (int m = 0; m < 4; ++m) {
        int row = wr*64 + m*16 + (lane & 15);
        af[m] = *(const short8*)(AsB + row*128 + krows);
      }
      #pragma unroll
      for (int n = 0; n < 4; ++n) {
        int row = wc*64 + n*16 + (lane & 15);
        bfr[n] = *(const short8*)(BsB + row*128 + krows);
      }
      #pragma unroll
      for (int m = 0; m < 4; ++m)
        #pragma unroll
        for (int n = 0; n < 4; ++n)
          acc[m][n] = __builtin_amdgcn_mfma_f32_16x16x32_bf16(af[m], bfr[n], acc[m][n], 0, 0, 0);
    }
  }
  #pragma unroll
  for (int m = 0; m < 4; ++m) {
    #pragma unroll
    for (int n = 0; n < 4; ++n) {
      const int col = bn + wc*64 + n*16 + (lane & 15);
      const float bv = biasp[col];
      const int dir = col >> 9;
      const int cc  = col & 511;
      #pragma unroll
      for (int jj = 0; jj < 4; ++jj) {
        const int row = bm + wr*64 + m*16 + ((lane >> 4)*4 + jj);
        xqd[((size_t)dir*NM + row)*512 + cc] = __float2bfloat16(acc[m][n][jj] + bv);
      }
    }
  }
}

// ---------------- LSTM: frozen R15 structure (two-phase, refill-after-consume) ----------------
__global__ __launch_bounds__(512) __attribute__((amdgpu_waves_per_eu(1, 2)))
void lstm_mfma(
    const __hip_bfloat16* __restrict__ xqd,   // [2][NM][512] packed j*4+g, bias folded, scaled
    const __hip_bfloat16* __restrict__ whhp,  // [2][512][128] permuted rows, scaled
    unsigned short* __restrict__ hf,          // [NM][128] bf16
    unsigned short* __restrict__ hb)          // [NM][128] bf16
{
  __shared__ __align__(16) char hfrag[2*4224];   // [buf][kc:1056B][lane:16B] B-frag layout
  __shared__ __align__(16) float z_lds[4*520];   // [b][4*swz(j)] f32x4, swizzled

  const int bid = blockIdx.x;
  const int dir = bid >> 3, bg = bid & 7;
  const int t = threadIdx.x;
  const int w = t >> 6, l = t & 63;
  const int ln = l & 15, lp = l >> 4;

  // A-fragments (weights): wave w rows (w*4+r)*16+ln, k = kc*32 + lp*8 + e.
  uint4 afu[4][4];
  {
    const char* wbase = (const char*)(whhp + (size_t)dir*512*128);
    #pragma unroll
    for (int r = 0; r < 4; ++r) {
      const int row = (w*4 + r)*16 + ln;
      #pragma unroll
      for (int kc = 0; kc < 4; ++kc)
        afu[r][kc] = *(const uint4*)(wbase + ((size_t)row*128 + lp*8 + kc*32)*2);
    }
  }

  for (int i = t; i < 2*4224/4; i += 512) ((int*)hfrag)[i] = 0;

  // phase-B identity
  const int b4 = t & 3, j = t >> 2;
  const int bsafe = bg*4 + b4;
  const int jsw = j ^ ((j >> 3) & 7);
  const int woff = (j >> 5)*1056 + ((j >> 3) & 3)*256 + b4*16 + (j & 7)*2;
  const int sdir = dir ? -1 : 1;
  const int s0 = dir ? 511 : 0;
  const ptrdiff_t xstep = (ptrdiff_t)sdir*512;
  const ptrdiff_t hstep = (ptrdiff_t)sdir*128;
  const __hip_bfloat16* xbase = xqd + ((size_t)dir*NM + (size_t)bsafe*512)*512
                                + (ptrdiff_t)s0*512 + j*4;
  unsigned short* hout = (dir ? hb : hf) + (size_t)bsafe*512*128 + (ptrdiff_t)s0*128 + j;

  float c = 0.f;

  // depth-4 x ring
  uint2 x0 = *(const uint2*)(xbase);
  uint2 x1 = *(const uint2*)(xbase + xstep);
  uint2 x2 = *(const uint2*)(xbase + 2*xstep);
  uint2 x3 = *(const uint2*)(xbase + 3*xstep);
  const __hip_bfloat16* xpre = xbase + 4*xstep;   // next address to fetch
  __syncthreads();   // prologue only

  int buf = 0;

  auto STEP = [&](uint2& xc, bool pf) {
    // ---- phase A: B-fragments (lane-linear, conflict-free) + 16 MFMA ----
    short8 bfv[4];
    #pragma unroll
    for (int kc = 0; kc < 4; ++kc)
      bfv[kc] = *(const short8*)(hfrag + buf*4224 + kc*1056 + l*16);

    f32x4 acc[4];
    #pragma unroll
    for (int r = 0; r < 4; ++r) {
      acc[r] = f32x4{0.f, 0.f, 0.f, 0.f};
      #pragma unroll
      for (int kc = 0; kc < 4; ++kc)
        acc[r] = __builtin_amdgcn_mfma_f32_16x16x32_bf16(
                   __builtin_bit_cast(short8, afu[r][kc]), bfv[kc], acc[r], 0, 0, 0);
    }

    // publish z (real batch cols ln<4 only), XOR-swizzled -> conflict-free
    if (ln < 4) {
      #pragma unroll
      for (int r = 0; r < 4; ++r) {
        const int jw = (w*4 + r)*4 + lp;
        const int js = jw ^ ((jw >> 3) & 7);
        *(f32x4*)&z_lds[ln*520 + 4*js] = acc[r];
      }
    }
    lds_barrier();

    // ---- phase B: one h per thread (exp2 forms, inputs pre-scaled) ----
    const f32x4 zv = *(const f32x4*)&z_lds[b4*520 + 4*jsw];
    const float zi = zv[0] + bflo(xc.x);
    const float zf = zv[1] + bfhi(xc.x);
    const float zg = zv[2] + bflo(xc.y);
    const float zo = zv[3] + bfhi(xc.y);
    const float I = rcpf_(1.f + ex2_(-zi));
    const float F = rcpf_(1.f + ex2_(-zf));
    const float G = 1.f - 2.f*rcpf_(ex2_(zg) + 1.f);
    const float O = rcpf_(1.f + ex2_(-zo));
    c = F*c + I*G;
    const float h = O*(1.f - 2.f*rcpf_(ex2_(c*LOG2E2) + 1.f));

    const unsigned short hbits =
        __builtin_bit_cast(unsigned short, __float2bfloat16(h));
    *(short*)(hfrag + (buf ^ 1)*4224 + woff) = (short)hbits;
    *hout = hbits;                     // fire-and-forget bf16 store
    hout += hstep;

    // refill AFTER consume: load directly into xc's register
    if (pf) { xc = *(const uint2*)xpre; xpre += xstep; }
    lds_barrier();
    buf ^= 1;
  };

  for (int it = 0; it < 127; ++it) {   // 508 steps with prefetch
    // AGPR pin (R9-proven residency mechanism)
    #pragma unroll
    for (int r = 0; r < 4; ++r)
      #pragma unroll
      for (int kc = 0; kc < 4; ++kc)
        asm volatile("" : "+a"(afu[r][kc].x), "+a"(afu[r][kc].y),
                          "+a"(afu[r][kc].z), "+a"(afu[r][kc].w));
    STEP(x0, true);
    STEP(x1, true);
    STEP(x2, true);
    STEP(x3, true);
  }
  // epilogue: last 4 steps, no prefetch
  STEP(x0, false);
  STEP(x1, false);
  STEP(x2, false);
  STEP(x3, false);
}

// ---------------- emissions: em[m][t] = [hf|hb][m] . Wp[t] + bp[t]  (bf16 h) ----------------
__global__ __launch_bounds__(128) void em_kernel(
    const unsigned short* __restrict__ hf, const unsigned short* __restrict__ hb,
    const float* __restrict__ Wp, const float* __restrict__ bp,
    float* __restrict__ em)
{
  __shared__ float wps[15*256];
  __shared__ float bps[15];
  const int tid = threadIdx.x;
  for (int i = tid; i < 15*256; i += 128) wps[i] = Wp[i];
  if (tid < 15) bps[tid] = bp[tid];
  __syncthreads();
  const size_t m = (size_t)blockIdx.x*128 + tid;
  float acc[15];
  #pragma unroll
  for (int t2 = 0; t2 < 15; ++t2) acc[t2] = bps[t2];
  const ushort4* hf4 = (const ushort4*)(hf + m*128);
  const ushort4* hb4 = (const ushort4*)(hb + m*128);
  for (int kc = 0; kc < 32; ++kc) {
    const ushort4 hv = hf4[kc];
    const float h0 = bfu(hv.x), h1 = bfu(hv.y), h2 = bfu(hv.z), h3 = bfu(hv.w);
    #pragma unroll
    for (int t2 = 0; t2 < 15; ++t2)
      acc[t2] += h0*wps[t2*256 + kc*4+0] + h1*wps[t2*256 + kc*4+1]
               + h2*wps[t2*256 + kc*4+2] + h3*wps[t2*256 + kc*4+3];
  }
  for (int kc = 0; kc < 32; ++kc) {
    const ushort4 hv = hb4[kc];
    const float h0 = bfu(hv.x), h1 = bfu(hv.y), h2 = bfu(hv.z), h3 = bfu(hv.w);
    #pragma unroll
    for (int t2 = 0; t2 < 15; ++t2)
      acc[t2] += h0*wps[t2*256 + 128 + kc*4+0] + h1*wps[t2*256 + 128 + kc*4+1]
               + h2*wps[t2*256 + 128 + kc*4+2] + h3*wps[t2*256 + 128 + kc*4+3];
  }
  float* eo = em + m*15;
  #pragma unroll
  for (int t2 = 0; t2 < 15; ++t2) eo[t2] = acc[t2];
}

// ---------------- CRF chunk scan: per-(batch, chunk-of-16-steps) transfer matrix ----------------
__global__ __launch_bounds__(64) void crf_chunks(
    const float* __restrict__ em,    // [32][512][15]
    const int* __restrict__ mask,    // [32][512]
    const float* __restrict__ trans, // [15][15]
    float* __restrict__ pmat)        // [32][32][240] (15x16 padded)
{
  __shared__ float trs[240];         // [k][j] padded stride 16
  __shared__ float cur[2][15][16];
  __shared__ float emc[16][16];
  __shared__ int mkc[16];
  const int b = blockIdx.x, cix = blockIdx.y;
  const int t = threadIdx.x;
  const int s0 = 1 + cix*16;
  const int ns = (512 - s0 < 16) ? (512 - s0) : 16;

  for (int e = t; e < 225; e += 64) trs[(e/15)*16 + (e%15)] = trans[e];
  for (int e = t; e < ns*15; e += 64) {
    const int k = e/15, j = e%15;
    emc[k][j] = em[((size_t)b*512 + s0 + k)*15 + j];
  }
  if (t < ns) mkc[t] = mask[b*512 + s0 + t];
  for (int e = t; e < 225; e += 64) {
    const int i = e/15, j = e%15;
    cur[0][i][j] = (i == j) ? 0.f : -1e30f;
  }
  __syncthreads();

  int cb = 0;
  for (int k = 0; k < ns; ++k) {
    if (mkc[k]) {                    // uniform branch (LDS value, same for all)
      for (int e = t; e < 225; e += 64) {
        const int i = e/15, j = e%15;
        float v[15];
        #pragma unroll
        for (int k2 = 0; k2 < 15; ++k2) v[k2] = cur[cb][i][k2] + trs[k2*16 + j];
        const float a01 = fmaxf(v[0], v[1]),  a23 = fmaxf(v[2], v[3]);
        const float a45 = fmaxf(v[4], v[5]),  a67 = fmaxf(v[6], v[7]);
        const float a89 = fmaxf(v[8], v[9]),  aab = fmaxf(v[10], v[11]);
        const float acd = fmaxf(v[12], v[13]);
        const float q0 = fmaxf(a01, a23), q1 = fmaxf(a45, a67);
        const float q2 = fmaxf(a89, aab), q3 = fmaxf(acd, v[14]);
        const float mx = fmaxf(fmaxf(q0, q1), fmaxf(q2, q3));
        float sum = 0.f;
        #pragma unroll
        for (int k2 = 0; k2 < 15; ++k2) sum += __expf(v[k2] - mx);
        cur[cb ^ 1][i][j] = emc[k][j] + mx + __logf(sum);
      }
      __syncthreads();
      cb ^= 1;
    }
  }
  float* P = pmat + ((size_t)b*32 + cix)*240;
  for (int e = t; e < 225; e += 64) {
    const int i = e/15, j = e%15;
    P[i*16 + j] = cur[cb][i][j];
  }
}

// ---------------- CRF final: alpha0 x P_0..P_31, logZ, gold score ----------------
__global__ __launch_bounds__(64) void crf_final(
    const float* __restrict__ em,
    const float* __restrict__ pmat,  // [32][32][240]
    const int* __restrict__ tags, const int* __restrict__ mask,
    const float* __restrict__ trans, const float* __restrict__ start_t,
    const float* __restrict__ end_t, float* __restrict__ nllb)
{
  __shared__ __align__(16) float ems[512*15];
  __shared__ float trs[225];
  __shared__ float Pl[240];
  __shared__ int tgs[512];
  __shared__ int mks[512];
  const int b = blockIdx.x, j = threadIdx.x;
  const float* emb = em + (size_t)b*512*15;
  {
    const float4* s4 = (const float4*)emb;
    float4* d4 = (float4*)ems;
    for (int i = j; i < 512*15/4; i += 64) d4[i] = s4[i];
    for (int i = j; i < 512; i += 64) { tgs[i] = tags[b*512+i]; mks[i] = mask[b*512+i]; }
    for (int i = j; i < 225; i += 64) trs[i] = trans[i];
  }
  __syncthreads();

  const int jc = (j < 15) ? j : 0;
  float alpha = (j < 15) ? (start_t[j] + ems[j]) : -1e30f;
  for (int cix = 0; cix < 32; ++cix) {
    const float* P = pmat + ((size_t)b*32 + cix)*240;
    __syncthreads();
    for (int e = j; e < 240; e += 64) Pl[e] = P[e];
    __syncthreads();
    float v[15];
    #pragma unroll
    for (int i = 0; i < 15; ++i) {
      const float ai = rdlane(alpha, i);
      v[i] = ai + Pl[i*16 + jc];
    }
    const float a01 = fmaxf(v[0], v[1]),  a23 = fmaxf(v[2], v[3]);
    const float a45 = fmaxf(v[4], v[5]),  a67 = fmaxf(v[6], v[7]);
    const float a89 = fmaxf(v[8], v[9]),  aab = fmaxf(v[10], v[11]);
    const float acd = fmaxf(v[12], v[13]);
    const float q0 = fmaxf(a01, a23), q1 = fmaxf(a45, a67);
    const float q2 = fmaxf(a89, aab), q3 = fmaxf(acd, v[14]);
    const float mx = fmaxf(fmaxf(q0, q1), fmaxf(q2, q3));
    float sum = 0.f;
    #pragma unroll
    for (int i = 0; i < 15; ++i) sum += __expf(v[i] - mx);
    const float nxt = mx + __logf(sum);
    if (j < 15) alpha = nxt;
  }

  float vz = (j < 15) ? (alpha + end_t[j]) : -1e30f;
  float mz = vz;
  #pragma unroll
  for (int off = 32; off > 0; off >>= 1) mz = fmaxf(mz, __shfl_xor(mz, off, 64));
  float se = (j < 15) ? __expf(vz - mz) : 0.f;
  #pragma unroll
  for (int off = 32; off > 0; off >>= 1) se += __shfl_xor(se, off, 64);
  const float logZ = mz + __logf(se);

  float sc = 0.f; int cnt = 0;
  for (int s = j; s < 512; s += 64) cnt += (mks[s] ? 1 : 0);
  for (int s = 1 + j; s < 512; s += 64) {
    if (mks[s]) {
      const int tp = tgs[s-1], tc = tgs[s];
      sc += trs[tp*15 + tc] + ems[s*15 + tc];
    }
  }
  #pragma unroll
  for (int off = 32; off > 0; off >>= 1) {
    sc  += __shfl_xor(sc, off, 64);
    cnt += __shfl_xor(cnt, off, 64);
  }
  if (j == 0) {
    const int t0 = tgs[0];
    sc += start_t[t0] + ems[t0];
    int last = cnt - 1; if (last < 0) last = 0;
    sc += end_t[tgs[last]];
    nllb[b] = logZ - sc;
  }
}

__global__ __launch_bounds__(64) void nll_reduce_kernel(const float* __restrict__ nllb,
                                                        float* __restrict__ out) {
  const int j = threadIdx.x;
  float v = (j < 32) ? nllb[j] : 0.f;
  #pragma unroll
  for (int off = 32; off > 0; off >>= 1) v += __shfl_xor(v, off, 64);
  if (j == 0) out[0] = v;
}

// ---------------- launch ----------------
extern "C" void kernel_launch(void* const* d_in, const int* in_sizes, int n_in,
                              void* d_out, int out_size, void* d_ws, size_t ws_size,
                              hipStream_t stream) {
  const float* x      = (const float*)d_in[0];
  const int*   tags   = (const int*)d_in[1];
  const int*   mask   = (const int*)d_in[2];
  const float* Wih_f  = (const float*)d_in[3];
  const float* Whh_f  = (const float*)d_in[4];
  const float* bih_f  = (const float*)d_in[5];
  const float* bhh_f  = (const float*)d_in[6];
  const float* Wih_b  = (const float*)d_in[7];
  const float* Whh_b  = (const float*)d_in[8];
  const float* bih_b  = (const float*)d_in[9];
  const float* bhh_b  = (const float*)d_in[10];
  const float* Wp     = (const float*)d_in[11];
  const float* bp     = (const float*)d_in[12];
  const float* trans  = (const float*)d_in[13];
  const float* start_t= (const float*)d_in[14];
  const float* end_t  = (const float*)d_in[15];
  float* out = (float*)d_out;

  char* ws = (char*)d_ws;
  size_t off = 0;
  auto alloc = [&](size_t bytes) { char* p = ws + off; off += (bytes + 255) & ~(size_t)255; return p; };
  __hip_bfloat16* xbf   = (__hip_bfloat16*)alloc((size_t)NM*NE*2);        // 25.2 MB
  __hip_bfloat16* Wihbf = (__hip_bfloat16*)alloc((size_t)1024*NE*2);      // 1.6 MB
  __hip_bfloat16* whhp  = (__hip_bfloat16*)alloc((size_t)2*512*128*2);    // 0.26 MB
  float*          biasp = (float*)alloc(1024*4);
  __hip_bfloat16* xqd   = (__hip_bfloat16*)alloc((size_t)2*NM*512*2);     // 33.6 MB
  unsigned short* hf    = (unsigned short*)alloc((size_t)NM*128*2);       // 4.2 MB
  unsigned short* hb    = (unsigned short*)alloc((size_t)NM*128*2);       // 4.2 MB
  float*          em    = (float*)alloc((size_t)NM*15*4);                 // 1.0 MB
  float*          pmat  = (float*)alloc((size_t)32*32*240*4);             // 1.0 MB
  float*          nllb  = (float*)alloc(32*4);
  (void)ws_size; (void)in_sizes; (void)n_in; (void)out_size;

  prep_all_kernel<<<3072, 256, 0, stream>>>(x, Wih_f, Wih_b, Whh_f, Whh_b,
                                            bih_f, bhh_f, bih_b, bhh_b,
                                            xbf, Wihbf, whhp, biasp);
  gemm_xproj<<<1024, 256, 0, stream>>>(xbf, Wihbf, biasp, xqd);
  lstm_mfma<<<16, 512, 0, stream>>>(xqd, whhp, hf, hb);
  em_kernel<<<128, 128, 0, stream>>>(hf, hb, Wp, bp, em);
  crf_chunks<<<dim3(32, 32), 64, 0, stream>>>(em, mask, trans, pmat);
  crf_final<<<32, 64, 0, stream>>>(em, pmat, tags, mask, trans, start_t, end_t, nllb);
  nll_reduce_kernel<<<1, 64, 0, stream>>>(nllb, out);
}

// Round 19
// 478.732 us; speedup vs baseline: 1.2682x; 1.0346x over previous
//
#include <hip/hip_runtime.h>
#include <hip/hip_bf16.h>
#include <cstdint>

typedef __attribute__((ext_vector_type(8))) short short8;
typedef __attribute__((ext_vector_type(4))) float f32x4;
typedef _Float16 f16x2 __attribute__((ext_vector_type(2)));

#define NS 512
#define NB 32
#define NE 768
#define NH 128
#define NT 15
#define NM (NB*NS)      // 16384 rows, m = b*512 + s

#define LOG2E  1.4426950408889634f
#define LOG2E2 2.8853900817779268f

__device__ __forceinline__ float bflo(unsigned int u){ return __builtin_bit_cast(float, u << 16); }
__device__ __forceinline__ float bfhi(unsigned int u){ return __builtin_bit_cast(float, u & 0xffff0000u); }
__device__ __forceinline__ float bfu(unsigned short u){ return __builtin_bit_cast(float, (unsigned)u << 16); }

__device__ __forceinline__ float fd2(unsigned int wp, unsigned int hp, float acc) {
#if __has_builtin(__builtin_amdgcn_fdot2)
  return __builtin_amdgcn_fdot2(__builtin_bit_cast(f16x2, wp),
                                __builtin_bit_cast(f16x2, hp), acc, false);
#else
  f16x2 a = __builtin_bit_cast(f16x2, wp);
  f16x2 b = __builtin_bit_cast(f16x2, hp);
  return acc + (float)a[0]*(float)b[0] + (float)a[1]*(float)b[1];
#endif
}

__device__ __forceinline__ float rcpf_(float x){
#if __has_builtin(__builtin_amdgcn_rcpf)
  return __builtin_amdgcn_rcpf(x);
#else
  return __fdividef(1.f, x);
#endif
}
__device__ __forceinline__ float ex2_(float x){
#if __has_builtin(__builtin_amdgcn_exp2f)
  return __builtin_amdgcn_exp2f(x);
#else
  return exp2f(x);
#endif
}

// raw workgroup barrier: LDS-drain only, global loads/stores stay in flight.
__device__ __forceinline__ void lds_barrier() {
  asm volatile("s_waitcnt lgkmcnt(0)" ::: "memory");
  __builtin_amdgcn_s_barrier();
  asm volatile("" ::: "memory");
}

__device__ __forceinline__ void gload16(const void* g, void* l) {
#if __has_builtin(__builtin_amdgcn_global_load_lds)
  __builtin_amdgcn_global_load_lds((const __attribute__((address_space(1))) void*)g,
                                   (__attribute__((address_space(3))) void*)l, 16, 0, 0);
#else
  *(uint4*)l = *(const uint4*)g;
#endif
}

__device__ __forceinline__ float rdlane(float v, int i){
#if __has_builtin(__builtin_amdgcn_readlane)
  return __builtin_bit_cast(float, __builtin_amdgcn_readlane(__builtin_bit_cast(int, v), i));
#else
  return __shfl(v, i, 64);
#endif
}

// ---------------- fused prep: x->bf16 (blocks 0..2047) + weight prep (2048..3071) ----------------
// Weight scale: log2e for gates i,f,o; 2*log2e for g -> activations use exp2 directly.
// Whh written as f16 (fdot2 path); Wih as bf16 (MFMA gemm).
__global__ void prep_all_kernel(
    const float* __restrict__ x,
    const float* __restrict__ wihf, const float* __restrict__ wihb,
    const float* __restrict__ whhf, const float* __restrict__ whhb,
    const float* __restrict__ bihf, const float* __restrict__ bhhf,
    const float* __restrict__ bihb, const float* __restrict__ bhhb,
    __hip_bfloat16* __restrict__ xbf,    // [NM][768]
    __hip_bfloat16* __restrict__ wihp,   // [1024][768]
    _Float16* __restrict__ whhp,         // [1024][128] f16, scaled
    float* __restrict__ biasp)           // [1024]
{
  const int blk = blockIdx.x;
  if (blk < 2048) {
    const int n4 = NM*NE/4;
    int i = blk*256 + threadIdx.x;
    int stride = 2048*256;
    for (int j = i; j < n4; j += stride) {
      float4 v = ((const float4*)x)[j];
      ushort4 o;
      o.x = __builtin_bit_cast(unsigned short, __float2bfloat16(v.x));
      o.y = __builtin_bit_cast(unsigned short, __float2bfloat16(v.y));
      o.z = __builtin_bit_cast(unsigned short, __float2bfloat16(v.z));
      o.w = __builtin_bit_cast(unsigned short, __float2bfloat16(v.w));
      ((ushort4*)xbf)[j] = o;
    }
  } else {
    const int n = blk - 2048;         // 0..1023, permuted row = dir*512 + (j*4+g)
    const int dir = n >> 9, cc = n & 511, j = cc >> 2, g = cc & 3;
    const float fac = (g == 2) ? LOG2E2 : LOG2E;
    const int srow = g*128 + j;
    const float* si = (dir ? wihb : wihf) + (size_t)srow*768;
    __hip_bfloat16* di = wihp + (size_t)n*768;
    for (int e = threadIdx.x; e < 768; e += 256) di[e] = __float2bfloat16(si[e]*fac);
    const float* sh = (dir ? whhb : whhf) + (size_t)srow*128;
    _Float16* dh = whhp + (size_t)n*128;
    if (threadIdx.x < 128) dh[threadIdx.x] = (_Float16)(sh[threadIdx.x]*fac);
    if (threadIdx.x == 0)
      biasp[n] = fac * (dir ? (bihb[srow] + bhhb[srow]) : (bihf[srow] + bhhf[srow]));
  }
}

// ---------------- xproj GEMM: A[16384x768] @ Bw[1024x768]^T -> xqd[2][NM][512] ----------------
// 1024 blocks (4/CU), bijective XCD swizzle, T2 both-sides LDS swizzle (R18).
__global__ __launch_bounds__(256, 4) void gemm_xproj(
    const __hip_bfloat16* __restrict__ A,
    const __hip_bfloat16* __restrict__ Bw,
    const float* __restrict__ biasp,
    __hip_bfloat16* __restrict__ xqd)        // [2][NM][512] packed j*4+g, scaled
{
  __shared__ __align__(16) __hip_bfloat16 As[128*64];
  __shared__ __align__(16) __hip_bfloat16 Bs[128*64];
  const int id  = blockIdx.x;
  const int swzb = (id & 7)*128 + (id >> 3);   // bijective: 1024 = 8 XCD x 128
  const int bm = (swzb >> 3) * 128;
  const int bn = (swzb & 7) * 128;
  const int tid = threadIdx.x;
  const int lane = tid & 63;
  const int wv = tid >> 6;
  const int wr = wv >> 1, wc = wv & 1;
  char* AsB = (char*)As;
  char* BsB = (char*)Bs;
  const char* Ab = (const char*)A;
  const char* Bb = (const char*)Bw;
  f32x4 acc[4][4] = {};

  for (int kt = 0; kt < 12; ++kt) {
    const int k0 = kt * 64;
    __syncthreads();
    #pragma unroll
    for (int i = 0; i < 4; ++i) {
      int fb = i*4096 + tid*16;       // linear LDS dest (gload_lds requirement)
      int r  = fb >> 7;
      int cb = fb & 127;
      int cbs = cb ^ ((r & 7) << 4);  // pre-swizzled SOURCE: LDS[r][u] = G[r][u^(r&7)]
      gload16(Ab + ((size_t)(bm + r)*768 + k0)*2 + cbs, AsB + fb);
      gload16(Bb + ((size_t)(bn + r)*768 + k0)*2 + cbs, BsB + fb);
    }
    __syncthreads();
    const int sw = ((lane & 7) << 4);
    #pragma unroll
    for (int ks = 0; ks < 2; ++ks) {
      const int krowb = ks*64 + ((lane >> 4) << 4);
      const int krows = krowb ^ sw;
      short8 af[4], bfr[4];
      #pragma unroll
      for (int m = 0; m < 4; ++m) {
        int row = wr*64 + m*16 + (lane & 15);
        af[m] = *(const short8*)(AsB + row*128 + krows);
      }
      #pragma unroll
      for (int n = 0; n < 4; ++n) {
        int row = wc*64 + n*16 + (lane & 15);
        bfr[n] = *(const short8*)(BsB + row*128 + krows);
      }
      #pragma unroll
      for (int m = 0; m < 4; ++m)
        #pragma unroll
        for (int n = 0; n < 4; ++n)
          acc[m][n] = __builtin_amdgcn_mfma_f32_16x16x32_bf16(af[m], bfr[n], acc[m][n], 0, 0, 0);
    }
  }
  #pragma unroll
  for (int m = 0; m < 4; ++m) {
    #pragma unroll
    for (int n = 0; n < 4; ++n) {
      const int col = bn + wc*64 + n*16 + (lane & 15);
      const float bv = biasp[col];
      const int dir = col >> 9;
      const int cc  = col & 511;
      #pragma unroll
      for (int jj = 0; jj < 4; ++jj) {
        const int row = bm + wr*64 + m*16 + ((lane >> 4)*4 + jj);
        xqd[((size_t)dir*NM + row)*512 + cc] = __float2bfloat16(acc[m][n][jj] + bv);
      }
    }
  }
}

// ---------------- LSTM: fdot2 quad structure, ONE barrier/step, resident weights ----------------
// 64 blocks = (dir, b): one chain per block. 512 threads: thread = (j = t>>2, q = t&3).
// Thread computes all 4 gates of h-index j over k-quarter q (64 f16-pair dwords,
// pinned once -> register-resident); 2-level shfl_xor butterfly completes the
// k-reduction in-quad; all 4 quad lanes compute h redundantly (all-lane act).
// h double-buffered in LDS (f16); single lds_barrier per step; depth-4 x ring.
__global__ __launch_bounds__(512) __attribute__((amdgpu_waves_per_eu(1, 2)))
void lstm_fdot(
    const __hip_bfloat16* __restrict__ xqd,   // [2][NM][512] packed j*4+g, bias folded, scaled
    const _Float16* __restrict__ whhp,        // [2][512][128] rows n=j*4+g, scaled
    unsigned short* __restrict__ hf,          // [NM][128] bf16
    unsigned short* __restrict__ hb)          // [NM][128] bf16
{
  __shared__ __align__(16) _Float16 h_lds[2][128];

  const int bid = blockIdx.x;          // 0..63
  const int dir = bid >> 5, b = bid & 31;
  const int t = threadIdx.x;
  const int j = t >> 2, q = t & 3;

  // weights: rows j*4+g (g=0..3), k-quarter q -> 4 x 16 dwords of f16 pairs
  unsigned int wq[4][16];
  {
    const _Float16* wrow = whhp + ((size_t)dir*512 + j*4)*128 + q*32;
    #pragma unroll
    for (int g = 0; g < 4; ++g) {
      const uint4* wp = (const uint4*)(wrow + g*128);
      #pragma unroll
      for (int i = 0; i < 4; ++i) {
        uint4 v = wp[i];
        wq[g][i*4+0] = v.x; wq[g][i*4+1] = v.y; wq[g][i*4+2] = v.z; wq[g][i*4+3] = v.w;
      }
    }
  }
  // pin ONCE before the loop: asm-defined values cannot be rematerialized
  #pragma unroll
  for (int g = 0; g < 4; ++g)
    #pragma unroll
    for (int p = 0; p < 16; ++p)
      asm volatile("" : "+v"(wq[g][p]));

  if (t < 128) h_lds[0][t] = (_Float16)0.f;

  const int sdir = dir ? -1 : 1;
  const int s0 = dir ? 511 : 0;
  const ptrdiff_t xstep = (ptrdiff_t)sdir*512;
  const ptrdiff_t hstep = (ptrdiff_t)sdir*128;
  const __hip_bfloat16* xbase = xqd + ((size_t)dir*NM + (size_t)b*512)*512
                                + (ptrdiff_t)s0*512 + j*4;
  unsigned short* hout = (dir ? hb : hf) + (size_t)b*512*128 + (ptrdiff_t)s0*128 + j;

  float c = 0.f;

  // depth-4 x ring (refill-after-consume)
  uint2 x0 = *(const uint2*)(xbase);
  uint2 x1 = *(const uint2*)(xbase + xstep);
  uint2 x2 = *(const uint2*)(xbase + 2*xstep);
  uint2 x3 = *(const uint2*)(xbase + 3*xstep);
  const __hip_bfloat16* xpre = xbase + 4*xstep;
  __syncthreads();   // prologue only

  int rb = 0;

  auto STEP = [&](uint2& xc, bool pf) {
    // h quarter from LDS (broadcast within same-q lanes; conflict-free)
    const uint4* h4 = (const uint4*)(&h_lds[rb][q*32]);
    const uint4 hA = h4[0], hB = h4[1], hC = h4[2], hD = h4[3];
    const unsigned int hq[16] = {hA.x,hA.y,hA.z,hA.w, hB.x,hB.y,hB.z,hB.w,
                                 hC.x,hC.y,hC.z,hC.w, hD.x,hD.y,hD.z,hD.w};
    float a0 = 0.f, a1 = 0.f, a2 = 0.f, a3 = 0.f;
    #pragma unroll
    for (int p = 0; p < 16; ++p) {
      const unsigned int hv = hq[p];
      a0 = fd2(wq[0][p], hv, a0);
      a1 = fd2(wq[1][p], hv, a1);
      a2 = fd2(wq[2][p], hv, a2);
      a3 = fd2(wq[3][p], hv, a3);
    }
    // butterfly over quad k-quarters (all 4 lanes end identical)
    a0 += __shfl_xor(a0, 1, 64); a1 += __shfl_xor(a1, 1, 64);
    a2 += __shfl_xor(a2, 1, 64); a3 += __shfl_xor(a3, 1, 64);
    a0 += __shfl_xor(a0, 2, 64); a1 += __shfl_xor(a1, 2, 64);
    a2 += __shfl_xor(a2, 2, 64); a3 += __shfl_xor(a3, 2, 64);

    // z = recurrent + x (bias folded, pre-scaled); exp2 activations
    const float zi = a0 + bflo(xc.x);
    const float zf = a1 + bfhi(xc.x);
    const float zg = a2 + bflo(xc.y);
    const float zo = a3 + bfhi(xc.y);
    const float I = rcpf_(1.f + ex2_(-zi));
    const float F = rcpf_(1.f + ex2_(-zf));
    const float G = 1.f - 2.f*rcpf_(ex2_(zg) + 1.f);
    const float O = rcpf_(1.f + ex2_(-zo));
    c = F*c + I*G;
    const float h = O*(1.f - 2.f*rcpf_(ex2_(c*LOG2E2) + 1.f));

    if (q == 0)      h_lds[rb ^ 1][j] = (_Float16)h;
    else if (q == 1) *hout = __builtin_bit_cast(unsigned short, __float2bfloat16(h));
    hout += hstep;

    // refill AFTER consume: straight into xc's register (no copy, no same-step wait)
    if (pf) { xc = *(const uint2*)xpre; xpre += xstep; }
    lds_barrier();                     // single barrier per step
    rb ^= 1;
  };

  for (int it = 0; it < 127; ++it) {   // 508 steps with prefetch
    STEP(x0, true);
    STEP(x1, true);
    STEP(x2, true);
    STEP(x3, true);
  }
  STEP(x0, false);
  STEP(x1, false);
  STEP(x2, false);
  STEP(x3, false);
}

// ---------------- emissions: em[m][t] = [hf|hb][m] . Wp[t] + bp[t]  (bf16 h) ----------------
__global__ __launch_bounds__(128) void em_kernel(
    const unsigned short* __restrict__ hf, const unsigned short* __restrict__ hb,
    const float* __restrict__ Wp, const float* __restrict__ bp,
    float* __restrict__ em)
{
  __shared__ float wps[15*256];
  __shared__ float bps[15];
  const int tid = threadIdx.x;
  for (int i = tid; i < 15*256; i += 128) wps[i] = Wp[i];
  if (tid < 15) bps[tid] = bp[tid];
  __syncthreads();
  const size_t m = (size_t)blockIdx.x*128 + tid;
  float acc[15];
  #pragma unroll
  for (int t2 = 0; t2 < 15; ++t2) acc[t2] = bps[t2];
  const ushort4* hf4 = (const ushort4*)(hf + m*128);
  const ushort4* hb4 = (const ushort4*)(hb + m*128);
  for (int kc = 0; kc < 32; ++kc) {
    const ushort4 hv = hf4[kc];
    const float h0 = bfu(hv.x), h1 = bfu(hv.y), h2 = bfu(hv.z), h3 = bfu(hv.w);
    #pragma unroll
    for (int t2 = 0; t2 < 15; ++t2)
      acc[t2] += h0*wps[t2*256 + kc*4+0] + h1*wps[t2*256 + kc*4+1]
               + h2*wps[t2*256 + kc*4+2] + h3*wps[t2*256 + kc*4+3];
  }
  for (int kc = 0; kc < 32; ++kc) {
    const ushort4 hv = hb4[kc];
    const float h0 = bfu(hv.x), h1 = bfu(hv.y), h2 = bfu(hv.z), h3 = bfu(hv.w);
    #pragma unroll
    for (int t2 = 0; t2 < 15; ++t2)
      acc[t2] += h0*wps[t2*256 + 128 + kc*4+0] + h1*wps[t2*256 + 128 + kc*4+1]
               + h2*wps[t2*256 + 128 + kc*4+2] + h3*wps[t2*256 + 128 + kc*4+3];
  }
  float* eo = em + m*15;
  #pragma unroll
  for (int t2 = 0; t2 < 15; ++t2) eo[t2] = acc[t2];
}

// ---------------- CRF chunk scan ----------------
__global__ __launch_bounds__(64) void crf_chunks(
    const float* __restrict__ em,    // [32][512][15]
    const int* __restrict__ mask,    // [32][512]
    const float* __restrict__ trans, // [15][15]
    float* __restrict__ pmat)        // [32][32][240] (15x16 padded)
{
  __shared__ float trs[240];
  __shared__ float cur[2][15][16];
  __shared__ float emc[16][16];
  __shared__ int mkc[16];
  const int b = blockIdx.x, cix = blockIdx.y;
  const int t = threadIdx.x;
  const int s0 = 1 + cix*16;
  const int ns = (512 - s0 < 16) ? (512 - s0) : 16;

  for (int e = t; e < 225; e += 64) trs[(e/15)*16 + (e%15)] = trans[e];
  for (int e = t; e < ns*15; e += 64) {
    const int k = e/15, j = e%15;
    emc[k][j] = em[((size_t)b*512 + s0 + k)*15 + j];
  }
  if (t < ns) mkc[t] = mask[b*512 + s0 + t];
  for (int e = t; e < 225; e += 64) {
    const int i = e/15, j = e%15;
    cur[0][i][j] = (i == j) ? 0.f : -1e30f;
  }
  __syncthreads();

  int cb = 0;
  for (int k = 0; k < ns; ++k) {
    if (mkc[k]) {
      for (int e = t; e < 225; e += 64) {
        const int i = e/15, j = e%15;
        float v[15];
        #pragma unroll
        for (int k2 = 0; k2 < 15; ++k2) v[k2] = cur[cb][i][k2] + trs[k2*16 + j];
        const float a01 = fmaxf(v[0], v[1]),  a23 = fmaxf(v[2], v[3]);
        const float a45 = fmaxf(v[4], v[5]),  a67 = fmaxf(v[6], v[7]);
        const float a89 = fmaxf(v[8], v[9]),  aab = fmaxf(v[10], v[11]);
        const float acd = fmaxf(v[12], v[13]);
        const float q0 = fmaxf(a01, a23), q1 = fmaxf(a45, a67);
        const float q2 = fmaxf(a89, aab), q3 = fmaxf(acd, v[14]);
        const float mx = fmaxf(fmaxf(q0, q1), fmaxf(q2, q3));
        float sum = 0.f;
        #pragma unroll
        for (int k2 = 0; k2 < 15; ++k2) sum += __expf(v[k2] - mx);
        cur[cb ^ 1][i][j] = emc[k][j] + mx + __logf(sum);
      }
      __syncthreads();
      cb ^= 1;
    }
  }
  float* P = pmat + ((size_t)b*32 + cix)*240;
  for (int e = t; e < 225; e += 64) {
    const int i = e/15, j = e%15;
    P[i*16 + j] = cur[cb][i][j];
  }
}

// ---------------- CRF final ----------------
__global__ __launch_bounds__(64) void crf_final(
    const float* __restrict__ em,
    const float* __restrict__ pmat,  // [32][32][240]
    const int* __restrict__ tags, const int* __restrict__ mask,
    const float* __restrict__ trans, const float* __restrict__ start_t,
    const float* __restrict__ end_t, float* __restrict__ nllb)
{
  __shared__ __align__(16) float ems[512*15];
  __shared__ float trs[225];
  __shared__ float Pl[240];
  __shared__ int tgs[512];
  __shared__ int mks[512];
  const int b = blockIdx.x, j = threadIdx.x;
  const float* emb = em + (size_t)b*512*15;
  {
    const float4* s4 = (const float4*)emb;
    float4* d4 = (float4*)ems;
    for (int i = j; i < 512*15/4; i += 64) d4[i] = s4[i];
    for (int i = j; i < 512; i += 64) { tgs[i] = tags[b*512+i]; mks[i] = mask[b*512+i]; }
    for (int i = j; i < 225; i += 64) trs[i] = trans[i];
  }
  __syncthreads();

  const int jc = (j < 15) ? j : 0;
  float alpha = (j < 15) ? (start_t[j] + ems[j]) : -1e30f;
  for (int cix = 0; cix < 32; ++cix) {
    const float* P = pmat + ((size_t)b*32 + cix)*240;
    __syncthreads();
    for (int e = j; e < 240; e += 64) Pl[e] = P[e];
    __syncthreads();
    float v[15];
    #pragma unroll
    for (int i = 0; i < 15; ++i) {
      const float ai = rdlane(alpha, i);
      v[i] = ai + Pl[i*16 + jc];
    }
    const float a01 = fmaxf(v[0], v[1]),  a23 = fmaxf(v[2], v[3]);
    const float a45 = fmaxf(v[4], v[5]),  a67 = fmaxf(v[6], v[7]);
    const float a89 = fmaxf(v[8], v[9]),  aab = fmaxf(v[10], v[11]);
    const float acd = fmaxf(v[12], v[13]);
    const float q0 = fmaxf(a01, a23), q1 = fmaxf(a45, a67);
    const float q2 = fmaxf(a89, aab), q3 = fmaxf(acd, v[14]);
    const float mx = fmaxf(fmaxf(q0, q1), fmaxf(q2, q3));
    float sum = 0.f;
    #pragma unroll
    for (int i = 0; i < 15; ++i) sum += __expf(v[i] - mx);
    const float nxt = mx + __logf(sum);
    if (j < 15) alpha = nxt;
  }

  float vz = (j < 15) ? (alpha + end_t[j]) : -1e30f;
  float mz = vz;
  #pragma unroll
  for (int off = 32; off > 0; off >>= 1) mz = fmaxf(mz, __shfl_xor(mz, off, 64));
  float se = (j < 15) ? __expf(vz - mz) : 0.f;
  #pragma unroll
  for (int off = 32; off > 0; off >>= 1) se += __shfl_xor(se, off, 64);
  const float logZ = mz + __logf(se);

  float sc = 0.f; int cnt = 0;
  for (int s = j; s < 512; s += 64) cnt += (mks[s] ? 1 : 0);
  for (int s = 1 + j; s < 512; s += 64) {
    if (mks[s]) {
      const int tp = tgs[s-1], tc = tgs[s];
      sc += trs[tp*15 + tc] + ems[s*15 + tc];
    }
  }
  #pragma unroll
  for (int off = 32; off > 0; off >>= 1) {
    sc  += __shfl_xor(sc, off, 64);
    cnt += __shfl_xor(cnt, off, 64);
  }
  if (j == 0) {
    const int t0 = tgs[0];
    sc += start_t[t0] + ems[t0];
    int last = cnt - 1; if (last < 0) last = 0;
    sc += end_t[tgs[last]];
    nllb[b] = logZ - sc;
  }
}

__global__ __launch_bounds__(64) void nll_reduce_kernel(const float* __restrict__ nllb,
                                                        float* __restrict__ out) {
  const int j = threadIdx.x;
  float v = (j < 32) ? nllb[j] : 0.f;
  #pragma unroll
  for (int off = 32; off > 0; off >>= 1) v += __shfl_xor(v, off, 64);
  if (j == 0) out[0] = v;
}

// ---------------- launch ----------------
extern "C" void kernel_launch(void* const* d_in, const int* in_sizes, int n_in,
                              void* d_out, int out_size, void* d_ws, size_t ws_size,
                              hipStream_t stream) {
  const float* x      = (const float*)d_in[0];
  const int*   tags   = (const int*)d_in[1];
  const int*   mask   = (const int*)d_in[2];
  const float* Wih_f  = (const float*)d_in[3];
  const float* Whh_f  = (const float*)d_in[4];
  const float* bih_f  = (const float*)d_in[5];
  const float* bhh_f  = (const float*)d_in[6];
  const float* Wih_b  = (const float*)d_in[7];
  const float* Whh_b  = (const float*)d_in[8];
  const float* bih_b  = (const float*)d_in[9];
  const float* bhh_b  = (const float*)d_in[10];
  const float* Wp     = (const float*)d_in[11];
  const float* bp     = (const float*)d_in[12];
  const float* trans  = (const float*)d_in[13];
  const float* start_t= (const float*)d_in[14];
  const float* end_t  = (const float*)d_in[15];
  float* out = (float*)d_out;

  char* ws = (char*)d_ws;
  size_t off = 0;
  auto alloc = [&](size_t bytes) { char* p = ws + off; off += (bytes + 255) & ~(size_t)255; return p; };
  __hip_bfloat16* xbf   = (__hip_bfloat16*)alloc((size_t)NM*NE*2);        // 25.2 MB
  __hip_bfloat16* Wihbf = (__hip_bfloat16*)alloc((size_t)1024*NE*2);      // 1.6 MB
  _Float16*       whhp  = (_Float16*)alloc((size_t)2*512*128*2);          // 0.26 MB
  float*          biasp = (float*)alloc(1024*4);
  __hip_bfloat16* xqd   = (__hip_bfloat16*)alloc((size_t)2*NM*512*2);     // 33.6 MB
  unsigned short* hf    = (unsigned short*)alloc((size_t)NM*128*2);       // 4.2 MB
  unsigned short* hb    = (unsigned short*)alloc((size_t)NM*128*2);       // 4.2 MB
  float*          em    = (float*)alloc((size_t)NM*15*4);                 // 1.0 MB
  float*          pmat  = (float*)alloc((size_t)32*32*240*4);             // 1.0 MB
  float*          nllb  = (float*)alloc(32*4);
  (void)ws_size; (void)in_sizes; (void)n_in; (void)out_size;

  prep_all_kernel<<<3072, 256, 0, stream>>>(x, Wih_f, Wih_b, Whh_f, Whh_b,
                                            bih_f, bhh_f, bih_b, bhh_b,
                                            xbf, Wihbf, whhp, biasp);
  gemm_xproj<<<1024, 256, 0, stream>>>(xbf, Wihbf, biasp, xqd);
  lstm_fdot<<<64, 512, 0, stream>>>(xqd, whhp, hf, hb);
  em_kernel<<<128, 128, 0, stream>>>(hf, hb, Wp, bp, em);
  crf_chunks<<<dim3(32, 32), 64, 0, stream>>>(em, mask, trans, pmat);
  crf_final<<<32, 64, 0, stream>>>(em, pmat, tags, mask, trans, start_t, end_t, nllb);
  nll_reduce_kernel<<<1, 64, 0, stream>>>(nllb, out);
}